// Round 1
// baseline (537.374 us; speedup 1.0000x reference)
//
#include <hip/hip_runtime.h>
#include <hip/hip_bf16.h>
#include <math.h>

#define BB 4
#define SS 512
#define DD 768
#define II 64
#define LL 2
#define HH 12
#define FF 3072

using short8 = __attribute__((ext_vector_type(8))) short;
using f32x4  = __attribute__((ext_vector_type(4))) float;

__device__ __forceinline__ unsigned short f2bf(float x) {
  return __builtin_bit_cast(unsigned short, __float2bfloat16(x));
}

__device__ __forceinline__ void gload_lds16(const void* g, void* l) {
  __builtin_amdgcn_global_load_lds((const __attribute__((address_space(1))) unsigned int*)g,
                                   (__attribute__((address_space(3))) unsigned int*)l, 16, 0, 0);
}

// ---------------- cast hs0/hs1 to bf16 ----------------
__global__ __launch_bounds__(256) void cast2_kernel(const float* __restrict__ a, const float* __restrict__ b,
                                                    unsigned short* __restrict__ oa, unsigned short* __restrict__ ob) {
  int idx = blockIdx.x * 256 + threadIdx.x;  // grid sized exactly: n/4 elements
  float4 va = ((const float4*)a)[idx];
  float4 vb = ((const float4*)b)[idx];
  union { unsigned short u[4]; uint2 v; } pa, pb;
  pa.u[0] = f2bf(va.x); pa.u[1] = f2bf(va.y); pa.u[2] = f2bf(va.z); pa.u[3] = f2bf(va.w);
  pb.u[0] = f2bf(vb.x); pb.u[1] = f2bf(vb.y); pb.u[2] = f2bf(vb.z); pb.u[3] = f2bf(vb.w);
  ((uint2*)oa)[idx] = pa.v;
  ((uint2*)ob)[idx] = pb.v;
}

// ---------------- transpose + cast weights: W[l][K][N] f32 -> WT[l][N][K] bf16 ----------------
__global__ __launch_bounds__(256) void tcast_kernel(const float* __restrict__ W, unsigned short* __restrict__ WT,
                                                    int K, int N) {
  __shared__ float tile[32][33];
  int l = blockIdx.z;
  const float* Ws = W + (size_t)l * K * N;
  unsigned short* WTs = WT + (size_t)l * N * K;
  int n0 = blockIdx.x * 32, k0 = blockIdx.y * 32;
  int tx = threadIdx.x, ty = threadIdx.y;  // (32,8)
  #pragma unroll
  for (int r = 0; r < 4; ++r) tile[ty + 8 * r][tx] = Ws[(size_t)(k0 + ty + 8 * r) * N + (n0 + tx)];
  __syncthreads();
  #pragma unroll
  for (int r = 0; r < 4; ++r) WTs[(size_t)(n0 + ty + 8 * r) * K + (k0 + tx)] = f2bf(tile[tx][ty + 8 * r]);
}

// ---------------- masked max pooling + zero_indic ----------------
__global__ __launch_bounds__(256) void pool_kernel(const float* __restrict__ hs0, const int* __restrict__ mask,
                                                   int* __restrict__ zi, float* __restrict__ qf,
                                                   unsigned short* __restrict__ qb) {
  int bi = blockIdx.x;  // b*II + i
  int b = bi >> 6, t = threadIdx.x;
  const int* mrow = mask + (size_t)bi * SS;
  int incl = 0;
  for (int s = t; s < SS; s += 256) incl |= (mrow[s] == 0);
  int any = __syncthreads_or(incl);
  int z = !any;
  if (t == 0) zi[bi] = z;
  const float* hb = hs0 + (size_t)b * SS * DD;
  float m0 = -3.4e38f, m1 = -3.4e38f, m2 = -3.4e38f;
  for (int s = 0; s < SS; ++s) {
    if (z || mrow[s] == 0) {  // wave-uniform branch
      const float* r = hb + (size_t)s * DD;
      m0 = fmaxf(m0, r[t]);
      m1 = fmaxf(m1, r[t + 256]);
      m2 = fmaxf(m2, r[t + 512]);
    }
  }
  size_t o = (size_t)bi * DD;
  qf[o + t] = m0; qf[o + t + 256] = m1; qf[o + t + 512] = m2;
  qb[o + t] = f2bf(m0); qb[o + t + 256] = f2bf(m1); qb[o + t + 512] = f2bf(m2);
}

// ---------------- NT GEMM: C[M,N] = A[M,K](bf16) * Bt[N,K](bf16)^T + bias ----------------
struct GB { const unsigned short* A; const unsigned short* Bt; const float* bias; void* C; int M; };

template <int GELU, int OUTBF>
__global__ __launch_bounds__(256) void gemm_nt(GB g0, GB g1, GB g2, int N, int K) {
  __shared__ unsigned short Al[128 * 64];
  __shared__ unsigned short Bl[128 * 64];
  GB g = (blockIdx.z == 0) ? g0 : (blockIdx.z == 1 ? g1 : g2);
  int bm = blockIdx.x, bn = blockIdx.y;
  if (bm * 128 >= g.M) return;
  int t = threadIdx.x, w = t >> 6, lane = t & 63;
  int hi = lane >> 4, lo = lane & 15;
  int wr = w >> 1, wc = w & 1;
  f32x4 acc[4][4] = {};
  const char* Abase = (const char*)g.A + (size_t)(bm * 128) * (size_t)K * 2;
  const char* Bbase = (const char*)g.Bt + (size_t)(bn * 128) * (size_t)K * 2;
  int rowbytes = K * 2;
  int KT = K >> 6;
  for (int kt = 0; kt < KT; ++kt) {
    int k0b = kt * 128;  // byte offset along K
    #pragma unroll
    for (int c = 0; c < 4; ++c) {
      int base = (c * 4 + w) << 10;       // wave-uniform LDS byte base
      int o = base + lane * 16;           // this lane's linear LDS slot
      int row = o >> 7, cb = o & 127;
      int scb = cb ^ ((row & 7) << 4);    // pre-swizzled source (m173 pattern)
      gload_lds16(Abase + (size_t)row * rowbytes + (k0b + scb), (char*)Al + base);
      gload_lds16(Bbase + (size_t)row * rowbytes + (k0b + scb), (char*)Bl + base);
    }
    __syncthreads();  // drains vmcnt before use
    #pragma unroll
    for (int kk = 0; kk < 2; ++kk) {
      short8 av[4], bv_[4];
      #pragma unroll
      for (int mi = 0; mi < 4; ++mi) {
        int r = wr * 64 + mi * 16 + lo;
        av[mi] = *(const short8*)((const char*)Al + r * 128 + ((kk * 64 + hi * 16) ^ ((r & 7) << 4)));
      }
      #pragma unroll
      for (int ni = 0; ni < 4; ++ni) {
        int r = wc * 64 + ni * 16 + lo;
        bv_[ni] = *(const short8*)((const char*)Bl + r * 128 + ((kk * 64 + hi * 16) ^ ((r & 7) << 4)));
      }
      #pragma unroll
      for (int mi = 0; mi < 4; ++mi)
        #pragma unroll
        for (int ni = 0; ni < 4; ++ni)
          acc[mi][ni] = __builtin_amdgcn_mfma_f32_16x16x32_bf16(av[mi], bv_[ni], acc[mi][ni], 0, 0, 0);
    }
    __syncthreads();
  }
  int mbase = bm * 128 + wr * 64;
  int nbase = bn * 128 + wc * 64;
  #pragma unroll
  for (int mi = 0; mi < 4; ++mi)
    #pragma unroll
    for (int ni = 0; ni < 4; ++ni)
      #pragma unroll
      for (int r = 0; r < 4; ++r) {
        int gm = mbase + mi * 16 + hi * 4 + r;
        int gn = nbase + ni * 16 + lo;
        float v = acc[mi][ni][r] + g.bias[gn];
        if (GELU) v = 0.5f * v * (1.0f + erff(v * 0.70710678118654752f));
        if (OUTBF) ((unsigned short*)g.C)[(size_t)gm * N + gn] = f2bf(v);
        else       ((float*)g.C)[(size_t)gm * N + gn] = v;
      }
}

// ---------------- attention: per (b,h, 16-query chunk) ----------------
__global__ __launch_bounds__(256) void attn_kernel(const float* __restrict__ qh, const float* __restrict__ kh,
                                                   const float* __restrict__ vh, const int* __restrict__ mask,
                                                   const int* __restrict__ zi, unsigned short* __restrict__ ctx) {
  __shared__ float P[16][520];
  __shared__ float rinv[16];
  int bh = blockIdx.x;
  int b = bh / HH, h = bh - b * HH;
  int i0 = blockIdx.y * 16;
  int t = threadIdx.x, w = t >> 6, l = t & 63;
  const float* kb = kh + (size_t)b * SS * DD + h * 64;
  // Phase 1: scores. wave w covers s in [w*128, w*128+128), two 64-wide halves (lane = s)
  for (int h2 = 0; h2 < 2; ++h2) {
    int s = w * 128 + h2 * 64 + l;
    float4 kr[16];
    const float4* kp = (const float4*)(kb + (size_t)s * DD);
    #pragma unroll
    for (int d = 0; d < 16; ++d) kr[d] = kp[d];
    for (int i = 0; i < 16; ++i) {
      int gi = b * II + i0 + i;
      const float4* qp = (const float4*)(qh + (size_t)gi * DD + h * 64);  // wave-uniform
      float sc = 0.f;
      #pragma unroll
      for (int d = 0; d < 16; ++d) {
        float4 q4 = qp[d];
        sc += q4.x * kr[d].x + q4.y * kr[d].y + q4.z * kr[d].z + q4.w * kr[d].w;
      }
      int mz = mask[(size_t)gi * SS + s];
      int zf = zi[gi];
      float ext = (mz && !zf) ? -10000.f : 0.f;
      P[i][s] = sc * 0.125f + ext;
    }
  }
  __syncthreads();
  // Phase 2: row softmax; wave w handles rows 4w..4w+3; strided (conflict-free) access
  #pragma unroll
  for (int a = 0; a < 4; ++a) {
    int i = w * 4 + a;
    float* row = P[i];
    float vals[8];
    float vmax = -3.4e38f;
    #pragma unroll
    for (int j = 0; j < 8; ++j) { vals[j] = row[l + 64 * j]; vmax = fmaxf(vmax, vals[j]); }
    #pragma unroll
    for (int o2 = 32; o2; o2 >>= 1) vmax = fmaxf(vmax, __shfl_xor(vmax, o2));
    float ssum = 0.f;
    #pragma unroll
    for (int j = 0; j < 8; ++j) { float e = __expf(vals[j] - vmax); vals[j] = e; ssum += e; }
    #pragma unroll
    for (int o2 = 32; o2; o2 >>= 1) ssum += __shfl_xor(ssum, o2);
    #pragma unroll
    for (int j = 0; j < 8; ++j) row[l + 64 * j] = vals[j];
    if (l == 0) rinv[i] = 1.0f / ssum;
  }
  __syncthreads();
  // Phase 3: PV. wave w rows 4w..4w+3, lane = dh
  const float* p0 = P[w * 4 + 0];
  const float* p1 = P[w * 4 + 1];
  const float* p2 = P[w * 4 + 2];
  const float* p3 = P[w * 4 + 3];
  const float* vb = vh + (size_t)b * SS * DD + h * 64 + l;
  float a0 = 0, a1 = 0, a2 = 0, a3 = 0;
  #pragma unroll 4
  for (int s = 0; s < SS; ++s) {
    float vv = vb[(size_t)s * DD];
    a0 += p0[s] * vv; a1 += p1[s] * vv; a2 += p2[s] * vv; a3 += p3[s] * vv;
  }
  size_t cb2 = (size_t)(b * II + i0) * DD + h * 64 + l;
  ctx[cb2 + (size_t)(w * 4 + 0) * DD] = f2bf(a0 * rinv[w * 4 + 0]);
  ctx[cb2 + (size_t)(w * 4 + 1) * DD] = f2bf(a1 * rinv[w * 4 + 1]);
  ctx[cb2 + (size_t)(w * 4 + 2) * DD] = f2bf(a2 * rinv[w * 4 + 2]);
  ctx[cb2 + (size_t)(w * 4 + 3) * DD] = f2bf(a3 * rinv[w * 4 + 3]);
}

// ---------------- residual + LayerNorm, writes f32 + bf16 ----------------
__global__ __launch_bounds__(256) void ln_kernel(const float* __restrict__ x, const float* __restrict__ y,
                                                 const float* __restrict__ g, const float* __restrict__ bb,
                                                 float* __restrict__ qf, unsigned short* __restrict__ qb) {
  __shared__ float r1[4], r2[4];
  int r = blockIdx.x, t = threadIdx.x;
  size_t o = (size_t)r * DD;
  float v0 = x[o + t] + y[o + t];
  float v1 = x[o + t + 256] + y[o + t + 256];
  float v2 = x[o + t + 512] + y[o + t + 512];
  float s = v0 + v1 + v2, ss = v0 * v0 + v1 * v1 + v2 * v2;
  #pragma unroll
  for (int o2 = 32; o2; o2 >>= 1) { s += __shfl_xor(s, o2); ss += __shfl_xor(ss, o2); }
  if ((t & 63) == 0) { r1[t >> 6] = s; r2[t >> 6] = ss; }
  __syncthreads();
  s = r1[0] + r1[1] + r1[2] + r1[3];
  ss = r2[0] + r2[1] + r2[2] + r2[3];
  float mean = s * (1.0f / DD);
  float var = ss * (1.0f / DD) - mean * mean;
  float inv = rsqrtf(var + 1e-12f);
  float w0 = (v0 - mean) * inv * g[t] + bb[t];
  float w1 = (v1 - mean) * inv * g[t + 256] + bb[t + 256];
  float w2 = (v2 - mean) * inv * g[t + 512] + bb[t + 512];
  qf[o + t] = w0; qf[o + t + 256] = w1; qf[o + t + 512] = w2;
  qb[o + t] = f2bf(w0); qb[o + t + 256] = f2bf(w1); qb[o + t + 512] = f2bf(w2);
}

// ---------------- final zero-context substitution ----------------
__global__ __launch_bounds__(256) void final_kernel(const float* __restrict__ q, const int* __restrict__ zi,
                                                    const float* __restrict__ zc, float* __restrict__ out) {
  int idx = blockIdx.x * 256 + threadIdx.x;  // grid exactly B*I*D/256
  int bi = idx / DD, d = idx - bi * DD;
  out[idx] = zi[bi] ? zc[d] : q[idx];
}

extern "C" void kernel_launch(void* const* d_in, const int* in_sizes, int n_in,
                              void* d_out, int out_size, void* d_ws, size_t ws_size,
                              hipStream_t stream) {
  (void)in_sizes; (void)n_in; (void)out_size; (void)ws_size;
  const float* hs0 = (const float*)d_in[0];
  const float* hs1 = (const float*)d_in[1];
  const float* Wq  = (const float*)d_in[3];
  const float* bq  = (const float*)d_in[4];
  const float* Wk  = (const float*)d_in[5];
  const float* bk  = (const float*)d_in[6];
  const float* Wv  = (const float*)d_in[7];
  const float* bv  = (const float*)d_in[8];
  const float* Wo  = (const float*)d_in[9];
  const float* bo  = (const float*)d_in[10];
  const float* ln1g = (const float*)d_in[11];
  const float* ln1b = (const float*)d_in[12];
  const float* W1  = (const float*)d_in[13];
  const float* b1  = (const float*)d_in[14];
  const float* W2  = (const float*)d_in[15];
  const float* b2  = (const float*)d_in[16];
  const float* ln2g = (const float*)d_in[17];
  const float* ln2b = (const float*)d_in[18];
  const float* zc  = (const float*)d_in[19];
  const int*   mask = (const int*)d_in[20];

  char* ws = (char*)d_ws;
  size_t off = 0;
  auto alloc = [&](size_t bytes) { size_t o = off; off += (bytes + 255) & ~(size_t)255; return o; };

  unsigned short* WqT = (unsigned short*)(ws + alloc((size_t)LL * DD * DD * 2));
  unsigned short* WkT = (unsigned short*)(ws + alloc((size_t)LL * DD * DD * 2));
  unsigned short* WvT = (unsigned short*)(ws + alloc((size_t)LL * DD * DD * 2));
  unsigned short* WoT = (unsigned short*)(ws + alloc((size_t)LL * DD * DD * 2));
  unsigned short* W1T = (unsigned short*)(ws + alloc((size_t)LL * FF * DD * 2));  // [L][F][D]
  unsigned short* W2T = (unsigned short*)(ws + alloc((size_t)LL * DD * FF * 2));  // [L][D][F]
  unsigned short* hsb = (unsigned short*)(ws + alloc((size_t)2 * BB * SS * DD * 2));
  float*          qf  = (float*)(ws + alloc((size_t)BB * II * DD * 4));
  unsigned short* qb  = (unsigned short*)(ws + alloc((size_t)BB * II * DD * 2));
  float*          qhb = (float*)(ws + alloc((size_t)BB * II * DD * 4));
  float*          khb = (float*)(ws + alloc((size_t)BB * SS * DD * 4));
  float*          vhb = (float*)(ws + alloc((size_t)BB * SS * DD * 4));
  unsigned short* ctxb = (unsigned short*)(ws + alloc((size_t)BB * II * DD * 2));
  float*          att_o = (float*)(ws + alloc((size_t)BB * II * DD * 4));
  unsigned short* ffh = (unsigned short*)(ws + alloc((size_t)BB * II * FF * 2));
  float*          ffo = (float*)(ws + alloc((size_t)BB * II * DD * 4));
  int*            zib = (int*)(ws + alloc((size_t)BB * II * 4));

  // --- weight transposes (f32 -> bf16 [N][K]) ---
  dim3 tb(32, 8);
  tcast_kernel<<<dim3(DD / 32, DD / 32, LL), tb, 0, stream>>>(Wq, WqT, DD, DD);
  tcast_kernel<<<dim3(DD / 32, DD / 32, LL), tb, 0, stream>>>(Wk, WkT, DD, DD);
  tcast_kernel<<<dim3(DD / 32, DD / 32, LL), tb, 0, stream>>>(Wv, WvT, DD, DD);
  tcast_kernel<<<dim3(DD / 32, DD / 32, LL), tb, 0, stream>>>(Wo, WoT, DD, DD);
  tcast_kernel<<<dim3(FF / 32, DD / 32, LL), tb, 0, stream>>>(W1, W1T, DD, FF);
  tcast_kernel<<<dim3(DD / 32, FF / 32, LL), tb, 0, stream>>>(W2, W2T, FF, DD);
  // --- hs0/hs1 -> bf16 ---
  cast2_kernel<<<(BB * SS * DD / 4) / 256, 256, 0, stream>>>(hs0, hs1, hsb, hsb + (size_t)BB * SS * DD);
  // --- pooling + zero_indic -> q ---
  pool_kernel<<<BB * II, 256, 0, stream>>>(hs0, mask, zib, qf, qb);

  for (int l = 0; l < LL; ++l) {
    const unsigned short* hsl = hsb + (size_t)l * BB * SS * DD;
    // fused K, V, Q projections
    GB gK = { hsl, WkT + (size_t)l * DD * DD, bk + l * DD, khb, BB * SS };
    GB gV = { hsl, WvT + (size_t)l * DD * DD, bv + l * DD, vhb, BB * SS };
    GB gQ = { qb,  WqT + (size_t)l * DD * DD, bq + l * DD, qhb, BB * II };
    gemm_nt<0, 0><<<dim3(16, 6, 3), 256, 0, stream>>>(gK, gV, gQ, DD, DD);
    // attention
    attn_kernel<<<dim3(BB * HH, 4), 256, 0, stream>>>(qhb, khb, vhb, mask, zib, ctxb);
    // Wo projection
    GB gO = { ctxb, WoT + (size_t)l * DD * DD, bo + l * DD, att_o, BB * II };
    gemm_nt<0, 0><<<dim3(2, 6, 1), 256, 0, stream>>>(gO, gO, gO, DD, DD);
    // LN1 (residual q + att_o)
    ln_kernel<<<BB * II, 256, 0, stream>>>(qf, att_o, ln1g + l * DD, ln1b + l * DD, qf, qb);
    // FFN1 (GELU, bf16 out)
    GB gF1 = { qb, W1T + (size_t)l * FF * DD, b1 + l * FF, ffh, BB * II };
    gemm_nt<1, 1><<<dim3(2, FF / 128, 1), 256, 0, stream>>>(gF1, gF1, gF1, FF, DD);
    // FFN2
    GB gF2 = { ffh, W2T + (size_t)l * DD * FF, b2 + l * DD, ffo, BB * II };
    gemm_nt<0, 0><<<dim3(2, 6, 1), 256, 0, stream>>>(gF2, gF2, gF2, DD, FF);
    // LN2
    ln_kernel<<<BB * II, 256, 0, stream>>>(qf, ffo, ln2g + l * DD, ln2b + l * DD, qf, qb);
  }
  // final substitution
  final_kernel<<<(BB * II * DD) / 256, 256, 0, stream>>>(qf, zib, zc, (float*)d_out);
}

// Round 2
// 380.321 us; speedup vs baseline: 1.4129x; 1.4129x over previous
//
#include <hip/hip_runtime.h>
#include <hip/hip_bf16.h>
#include <math.h>

#define BB 4
#define SS 512
#define DD 768
#define II 64
#define LL 2
#define HH 12
#define FF 3072

using short8 = __attribute__((ext_vector_type(8))) short;
using f32x4  = __attribute__((ext_vector_type(4))) float;

__device__ __forceinline__ unsigned short f2bf(float x) {
  return __builtin_bit_cast(unsigned short, __float2bfloat16(x));
}

__device__ __forceinline__ void gload_lds16(const void* g, void* l) {
  __builtin_amdgcn_global_load_lds((const __attribute__((address_space(1))) unsigned int*)g,
                                   (__attribute__((address_space(3))) unsigned int*)l, 16, 0, 0);
}

// ---------------- cast hs0/hs1 to bf16 ----------------
__global__ __launch_bounds__(256) void cast2_kernel(const float* __restrict__ a, const float* __restrict__ b,
                                                    unsigned short* __restrict__ oa, unsigned short* __restrict__ ob) {
  int idx = blockIdx.x * 256 + threadIdx.x;  // grid sized exactly: n/4 elements
  float4 va = ((const float4*)a)[idx];
  float4 vb = ((const float4*)b)[idx];
  union { unsigned short u[4]; uint2 v; } pa, pb;
  pa.u[0] = f2bf(va.x); pa.u[1] = f2bf(va.y); pa.u[2] = f2bf(va.z); pa.u[3] = f2bf(va.w);
  pb.u[0] = f2bf(vb.x); pb.u[1] = f2bf(vb.y); pb.u[2] = f2bf(vb.z); pb.u[3] = f2bf(vb.w);
  ((uint2*)oa)[idx] = pa.v;
  ((uint2*)ob)[idx] = pb.v;
}

// ---------------- batched transpose+cast for the 4 square weights ----------------
struct T4 { const float* s[4]; };

__global__ __launch_bounds__(256) void tcast4_kernel(T4 src, unsigned short* __restrict__ dst) {
  __shared__ float tile[32][33];
  int z = blockIdx.z;              // widx*LL + l
  int widx = z >> 1, l = z & 1;
  const float* Ws = src.s[widx] + (size_t)l * DD * DD;
  unsigned short* WTs = dst + ((size_t)widx * LL + l) * DD * DD;
  int n0 = blockIdx.x * 32, k0 = blockIdx.y * 32;
  int tx = threadIdx.x, ty = threadIdx.y;  // (32,8)
  #pragma unroll
  for (int r = 0; r < 4; ++r) tile[ty + 8 * r][tx] = Ws[(size_t)(k0 + ty + 8 * r) * DD + (n0 + tx)];
  __syncthreads();
  #pragma unroll
  for (int r = 0; r < 4; ++r) WTs[(size_t)(n0 + ty + 8 * r) * DD + (k0 + tx)] = f2bf(tile[tx][ty + 8 * r]);
}

// ---------------- transpose + cast: W[l][K][N] f32 -> WT[l][N][K] bf16 ----------------
__global__ __launch_bounds__(256) void tcast_kernel(const float* __restrict__ W, unsigned short* __restrict__ WT,
                                                    int K, int N) {
  __shared__ float tile[32][33];
  int l = blockIdx.z;
  const float* Ws = W + (size_t)l * K * N;
  unsigned short* WTs = WT + (size_t)l * N * K;
  int n0 = blockIdx.x * 32, k0 = blockIdx.y * 32;
  int tx = threadIdx.x, ty = threadIdx.y;  // (32,8)
  #pragma unroll
  for (int r = 0; r < 4; ++r) tile[ty + 8 * r][tx] = Ws[(size_t)(k0 + ty + 8 * r) * N + (n0 + tx)];
  __syncthreads();
  #pragma unroll
  for (int r = 0; r < 4; ++r) WTs[(size_t)(n0 + ty + 8 * r) * K + (k0 + tx)] = f2bf(tile[tx][ty + 8 * r]);
}

// ---------------- masked max pooling + zero_indic (branchless, 3 blocks per span) ----------------
__global__ __launch_bounds__(256) void pool_kernel(const float* __restrict__ hs0, const int* __restrict__ mask,
                                                   int* __restrict__ zi, float* __restrict__ qf,
                                                   unsigned short* __restrict__ qb) {
  __shared__ float eadd[SS];
  int bi = blockIdx.x;  // b*II + i
  int b = bi >> 6, dz = blockIdx.y, t = threadIdx.x;
  const int* mrow = mask + (size_t)bi * SS;
  int incl = 0;
  for (int s = t; s < SS; s += 256) {
    int m = mrow[s];
    eadd[s] = m ? -__builtin_inff() : 0.0f;
    incl |= (m == 0);
  }
  int any = __syncthreads_or(incl);
  if (dz == 0 && t == 0) zi[bi] = !any;
  const float* hb = hs0 + (size_t)b * SS * DD + dz * 256 + t;
  float m[8];
  #pragma unroll
  for (int j = 0; j < 8; ++j) m[j] = -3.4e38f;
  for (int s0 = 0; s0 < SS; s0 += 8) {
    #pragma unroll
    for (int j = 0; j < 8; ++j)
      m[j] = fmaxf(m[j], hb[(size_t)(s0 + j) * DD] + eadd[s0 + j]);
  }
  float mm = fmaxf(fmaxf(fmaxf(m[0], m[1]), fmaxf(m[2], m[3])),
                   fmaxf(fmaxf(m[4], m[5]), fmaxf(m[6], m[7])));
  size_t o = (size_t)bi * DD + dz * 256 + t;
  qf[o] = mm;
  qb[o] = f2bf(mm);
}

// ---------------- NT GEMM 128x128: C[M,N] = A[M,K](bf16) * Bt[N,K](bf16)^T + bias ----------------
struct GB { const unsigned short* A; const unsigned short* Bt; const float* bias; void* C; int M; };

template <int GELU, int OUTBF>
__global__ __launch_bounds__(256) void gemm_nt(GB g0, GB g1, GB g2, int N, int K) {
  __shared__ unsigned short Al[128 * 64];
  __shared__ unsigned short Bl[128 * 64];
  GB g = (blockIdx.z == 0) ? g0 : (blockIdx.z == 1 ? g1 : g2);
  int bm = blockIdx.x, bn = blockIdx.y;
  if (bm * 128 >= g.M) return;
  int t = threadIdx.x, w = t >> 6, lane = t & 63;
  int hi = lane >> 4, lo = lane & 15;
  int wr = w >> 1, wc = w & 1;
  f32x4 acc[4][4] = {};
  const char* Abase = (const char*)g.A + (size_t)(bm * 128) * (size_t)K * 2;
  const char* Bbase = (const char*)g.Bt + (size_t)(bn * 128) * (size_t)K * 2;
  int rowbytes = K * 2;
  int KT = K >> 6;
  for (int kt = 0; kt < KT; ++kt) {
    int k0b = kt * 128;  // byte offset along K
    #pragma unroll
    for (int c = 0; c < 4; ++c) {
      int base = (c * 4 + w) << 10;       // wave-uniform LDS byte base
      int o = base + lane * 16;           // this lane's linear LDS slot
      int row = o >> 7, cb = o & 127;
      int scb = cb ^ ((row & 7) << 4);    // pre-swizzled source (m173 pattern)
      gload_lds16(Abase + (size_t)row * rowbytes + (k0b + scb), (char*)Al + base);
      gload_lds16(Bbase + (size_t)row * rowbytes + (k0b + scb), (char*)Bl + base);
    }
    __syncthreads();  // drains vmcnt before use
    #pragma unroll
    for (int kk = 0; kk < 2; ++kk) {
      short8 av[4], bv_[4];
      #pragma unroll
      for (int mi = 0; mi < 4; ++mi) {
        int r = wr * 64 + mi * 16 + lo;
        av[mi] = *(const short8*)((const char*)Al + r * 128 + ((kk * 64 + hi * 16) ^ ((r & 7) << 4)));
      }
      #pragma unroll
      for (int ni = 0; ni < 4; ++ni) {
        int r = wc * 64 + ni * 16 + lo;
        bv_[ni] = *(const short8*)((const char*)Bl + r * 128 + ((kk * 64 + hi * 16) ^ ((r & 7) << 4)));
      }
      #pragma unroll
      for (int mi = 0; mi < 4; ++mi)
        #pragma unroll
        for (int ni = 0; ni < 4; ++ni)
          acc[mi][ni] = __builtin_amdgcn_mfma_f32_16x16x32_bf16(av[mi], bv_[ni], acc[mi][ni], 0, 0, 0);
    }
    __syncthreads();
  }
  int mbase = bm * 128 + wr * 64;
  int nbase = bn * 128 + wc * 64;
  #pragma unroll
  for (int mi = 0; mi < 4; ++mi)
    #pragma unroll
    for (int ni = 0; ni < 4; ++ni)
      #pragma unroll
      for (int r = 0; r < 4; ++r) {
        int gm = mbase + mi * 16 + hi * 4 + r;
        int gn = nbase + ni * 16 + lo;
        float v = acc[mi][ni][r] + g.bias[gn];
        if (GELU) v = 0.5f * v * (1.0f + erff(v * 0.70710678118654752f));
        if (OUTBF) ((unsigned short*)g.C)[(size_t)gm * N + gn] = f2bf(v);
        else       ((float*)g.C)[(size_t)gm * N + gn] = v;
      }
}

// ---------------- NT GEMM 64x64 (for small-M projections): 4 waves x 32x32 ----------------
template <int GELU, int OUTBF>
__global__ __launch_bounds__(256) void gemm_nt64(GB g, int N, int K) {
  __shared__ unsigned short Al[64 * 64];
  __shared__ unsigned short Bl[64 * 64];
  int bm = blockIdx.x, bn = blockIdx.y;
  int t = threadIdx.x, w = t >> 6, lane = t & 63;
  int hi = lane >> 4, lo = lane & 15;
  int wr = w >> 1, wc = w & 1;
  f32x4 acc[2][2] = {};
  const char* Abase = (const char*)g.A + (size_t)(bm * 64) * (size_t)K * 2;
  const char* Bbase = (const char*)g.Bt + (size_t)(bn * 64) * (size_t)K * 2;
  int rowbytes = K * 2;
  int KT = K >> 6;
  for (int kt = 0; kt < KT; ++kt) {
    int k0b = kt * 128;
    #pragma unroll
    for (int c = 0; c < 2; ++c) {
      int base = (c * 4 + w) << 10;
      int o = base + lane * 16;
      int row = o >> 7, cb = o & 127;
      int scb = cb ^ ((row & 7) << 4);
      gload_lds16(Abase + (size_t)row * rowbytes + (k0b + scb), (char*)Al + base);
      gload_lds16(Bbase + (size_t)row * rowbytes + (k0b + scb), (char*)Bl + base);
    }
    __syncthreads();
    #pragma unroll
    for (int kk = 0; kk < 2; ++kk) {
      short8 av[2], bv_[2];
      #pragma unroll
      for (int mi = 0; mi < 2; ++mi) {
        int r = wr * 32 + mi * 16 + lo;
        av[mi] = *(const short8*)((const char*)Al + r * 128 + ((kk * 64 + hi * 16) ^ ((r & 7) << 4)));
      }
      #pragma unroll
      for (int ni = 0; ni < 2; ++ni) {
        int r = wc * 32 + ni * 16 + lo;
        bv_[ni] = *(const short8*)((const char*)Bl + r * 128 + ((kk * 64 + hi * 16) ^ ((r & 7) << 4)));
      }
      #pragma unroll
      for (int mi = 0; mi < 2; ++mi)
        #pragma unroll
        for (int ni = 0; ni < 2; ++ni)
          acc[mi][ni] = __builtin_amdgcn_mfma_f32_16x16x32_bf16(av[mi], bv_[ni], acc[mi][ni], 0, 0, 0);
    }
    __syncthreads();
  }
  int mbase = bm * 64 + wr * 32;
  int nbase = bn * 64 + wc * 32;
  #pragma unroll
  for (int mi = 0; mi < 2; ++mi)
    #pragma unroll
    for (int ni = 0; ni < 2; ++ni)
      #pragma unroll
      for (int r = 0; r < 4; ++r) {
        int gm = mbase + mi * 16 + hi * 4 + r;
        int gn = nbase + ni * 16 + lo;
        float v = acc[mi][ni][r] + g.bias[gn];
        if (GELU) v = 0.5f * v * (1.0f + erff(v * 0.70710678118654752f));
        if (OUTBF) ((unsigned short*)g.C)[(size_t)gm * N + gn] = f2bf(v);
        else       ((float*)g.C)[(size_t)gm * N + gn] = v;
      }
}

// ---------------- attention: per (b,h, 16-query chunk) ----------------
__global__ __launch_bounds__(256) void attn_kernel(const float* __restrict__ qh, const float* __restrict__ kh,
                                                   const float* __restrict__ vh, const int* __restrict__ mask,
                                                   const int* __restrict__ zi, unsigned short* __restrict__ ctx) {
  __shared__ float P[16][520];
  __shared__ float rinv[16];
  int bh = blockIdx.x;
  int b = bh / HH, h = bh - b * HH;
  int i0 = blockIdx.y * 16;
  int t = threadIdx.x, w = t >> 6, l = t & 63;
  const float* kb = kh + (size_t)b * SS * DD + h * 64;
  // Phase 1: scores. wave w covers s in [w*128, w*128+128), two 64-wide halves (lane = s)
  for (int h2 = 0; h2 < 2; ++h2) {
    int s = w * 128 + h2 * 64 + l;
    float4 kr[16];
    const float4* kp = (const float4*)(kb + (size_t)s * DD);
    #pragma unroll
    for (int d = 0; d < 16; ++d) kr[d] = kp[d];
    for (int i = 0; i < 16; ++i) {
      int gi = b * II + i0 + i;
      const float4* qp = (const float4*)(qh + (size_t)gi * DD + h * 64);  // wave-uniform
      float sc = 0.f;
      #pragma unroll
      for (int d = 0; d < 16; ++d) {
        float4 q4 = qp[d];
        sc += q4.x * kr[d].x + q4.y * kr[d].y + q4.z * kr[d].z + q4.w * kr[d].w;
      }
      int mz = mask[(size_t)gi * SS + s];
      int zf = zi[gi];
      float ext = (mz && !zf) ? -10000.f : 0.f;
      P[i][s] = sc * 0.125f + ext;
    }
  }
  __syncthreads();
  // Phase 2: row softmax; wave w handles rows 4w..4w+3; strided (conflict-free) access
  #pragma unroll
  for (int a = 0; a < 4; ++a) {
    int i = w * 4 + a;
    float* row = P[i];
    float vals[8];
    float vmax = -3.4e38f;
    #pragma unroll
    for (int j = 0; j < 8; ++j) { vals[j] = row[l + 64 * j]; vmax = fmaxf(vmax, vals[j]); }
    #pragma unroll
    for (int o2 = 32; o2; o2 >>= 1) vmax = fmaxf(vmax, __shfl_xor(vmax, o2));
    float ssum = 0.f;
    #pragma unroll
    for (int j = 0; j < 8; ++j) { float e = __expf(vals[j] - vmax); vals[j] = e; ssum += e; }
    #pragma unroll
    for (int o2 = 32; o2; o2 >>= 1) ssum += __shfl_xor(ssum, o2);
    #pragma unroll
    for (int j = 0; j < 8; ++j) row[l + 64 * j] = vals[j];
    if (l == 0) rinv[i] = 1.0f / ssum;
  }
  __syncthreads();
  // Phase 3: PV. wave w rows 4w..4w+3, lane = dh
  const float* p0 = P[w * 4 + 0];
  const float* p1 = P[w * 4 + 1];
  const float* p2 = P[w * 4 + 2];
  const float* p3 = P[w * 4 + 3];
  const float* vb = vh + (size_t)b * SS * DD + h * 64 + l;
  float a0 = 0, a1 = 0, a2 = 0, a3 = 0;
  #pragma unroll 4
  for (int s = 0; s < SS; ++s) {
    float vv = vb[(size_t)s * DD];
    a0 += p0[s] * vv; a1 += p1[s] * vv; a2 += p2[s] * vv; a3 += p3[s] * vv;
  }
  size_t cb2 = (size_t)(b * II + i0) * DD + h * 64 + l;
  ctx[cb2 + (size_t)(w * 4 + 0) * DD] = f2bf(a0 * rinv[w * 4 + 0]);
  ctx[cb2 + (size_t)(w * 4 + 1) * DD] = f2bf(a1 * rinv[w * 4 + 1]);
  ctx[cb2 + (size_t)(w * 4 + 2) * DD] = f2bf(a2 * rinv[w * 4 + 2]);
  ctx[cb2 + (size_t)(w * 4 + 3) * DD] = f2bf(a3 * rinv[w * 4 + 3]);
}

// ---------------- residual + LayerNorm, writes f32 + bf16 ----------------
__global__ __launch_bounds__(256) void ln_kernel(const float* __restrict__ x, const float* __restrict__ y,
                                                 const float* __restrict__ g, const float* __restrict__ bb,
                                                 float* __restrict__ qf, unsigned short* __restrict__ qb) {
  __shared__ float r1[4], r2[4];
  int r = blockIdx.x, t = threadIdx.x;
  size_t o = (size_t)r * DD;
  float v0 = x[o + t] + y[o + t];
  float v1 = x[o + t + 256] + y[o + t + 256];
  float v2 = x[o + t + 512] + y[o + t + 512];
  float s = v0 + v1 + v2, ss = v0 * v0 + v1 * v1 + v2 * v2;
  #pragma unroll
  for (int o2 = 32; o2; o2 >>= 1) { s += __shfl_xor(s, o2); ss += __shfl_xor(ss, o2); }
  if ((t & 63) == 0) { r1[t >> 6] = s; r2[t >> 6] = ss; }
  __syncthreads();
  s = r1[0] + r1[1] + r1[2] + r1[3];
  ss = r2[0] + r2[1] + r2[2] + r2[3];
  float mean = s * (1.0f / DD);
  float var = ss * (1.0f / DD) - mean * mean;
  float inv = rsqrtf(var + 1e-12f);
  float w0 = (v0 - mean) * inv * g[t] + bb[t];
  float w1 = (v1 - mean) * inv * g[t + 256] + bb[t + 256];
  float w2 = (v2 - mean) * inv * g[t + 512] + bb[t + 512];
  qf[o + t] = w0; qf[o + t + 256] = w1; qf[o + t + 512] = w2;
  qb[o + t] = f2bf(w0); qb[o + t + 256] = f2bf(w1); qb[o + t + 512] = f2bf(w2);
}

// ---------------- final zero-context substitution ----------------
__global__ __launch_bounds__(256) void final_kernel(const float* __restrict__ q, const int* __restrict__ zi,
                                                    const float* __restrict__ zc, float* __restrict__ out) {
  int idx = blockIdx.x * 256 + threadIdx.x;  // grid exactly B*I*D/256
  int bi = idx / DD, d = idx - bi * DD;
  out[idx] = zi[bi] ? zc[d] : q[idx];
}

extern "C" void kernel_launch(void* const* d_in, const int* in_sizes, int n_in,
                              void* d_out, int out_size, void* d_ws, size_t ws_size,
                              hipStream_t stream) {
  (void)in_sizes; (void)n_in; (void)out_size; (void)ws_size;
  const float* hs0 = (const float*)d_in[0];
  const float* hs1 = (const float*)d_in[1];
  const float* Wq  = (const float*)d_in[3];
  const float* bq  = (const float*)d_in[4];
  const float* Wk  = (const float*)d_in[5];
  const float* bk  = (const float*)d_in[6];
  const float* Wv  = (const float*)d_in[7];
  const float* bv  = (const float*)d_in[8];
  const float* Wo  = (const float*)d_in[9];
  const float* bo  = (const float*)d_in[10];
  const float* ln1g = (const float*)d_in[11];
  const float* ln1b = (const float*)d_in[12];
  const float* W1  = (const float*)d_in[13];
  const float* b1  = (const float*)d_in[14];
  const float* W2  = (const float*)d_in[15];
  const float* b2  = (const float*)d_in[16];
  const float* ln2g = (const float*)d_in[17];
  const float* ln2b = (const float*)d_in[18];
  const float* zc  = (const float*)d_in[19];
  const int*   mask = (const int*)d_in[20];

  char* ws = (char*)d_ws;
  size_t off = 0;
  auto alloc = [&](size_t bytes) { size_t o = off; off += (bytes + 255) & ~(size_t)255; return o; };

  unsigned short* WT4 = (unsigned short*)(ws + alloc((size_t)4 * LL * DD * DD * 2));  // [Wq,Wk,Wv,Wo][L][D][D]
  unsigned short* W1T = (unsigned short*)(ws + alloc((size_t)LL * FF * DD * 2));      // [L][F][D]
  unsigned short* W2T = (unsigned short*)(ws + alloc((size_t)LL * DD * FF * 2));      // [L][D][F]
  unsigned short* hsb = (unsigned short*)(ws + alloc((size_t)2 * BB * SS * DD * 2));
  float*          qf  = (float*)(ws + alloc((size_t)BB * II * DD * 4));
  unsigned short* qb  = (unsigned short*)(ws + alloc((size_t)BB * II * DD * 2));
  float*          qhb = (float*)(ws + alloc((size_t)BB * II * DD * 4));
  float*          khb = (float*)(ws + alloc((size_t)BB * SS * DD * 4));
  float*          vhb = (float*)(ws + alloc((size_t)BB * SS * DD * 4));
  unsigned short* ctxb = (unsigned short*)(ws + alloc((size_t)BB * II * DD * 2));
  float*          att_o = (float*)(ws + alloc((size_t)BB * II * DD * 4));
  unsigned short* ffh = (unsigned short*)(ws + alloc((size_t)BB * II * FF * 2));
  float*          ffo = (float*)(ws + alloc((size_t)BB * II * DD * 4));
  int*            zib = (int*)(ws + alloc((size_t)BB * II * 4));

  unsigned short* WqT = WT4 + 0 * (size_t)LL * DD * DD;
  unsigned short* WkT = WT4 + 1 * (size_t)LL * DD * DD;
  unsigned short* WvT = WT4 + 2 * (size_t)LL * DD * DD;
  unsigned short* WoT = WT4 + 3 * (size_t)LL * DD * DD;

  // --- weight transposes (f32 -> bf16 [N][K]) ---
  dim3 tb(32, 8);
  T4 t4 = { { Wq, Wk, Wv, Wo } };
  tcast4_kernel<<<dim3(DD / 32, DD / 32, 4 * LL), tb, 0, stream>>>(t4, WT4);
  tcast_kernel<<<dim3(FF / 32, DD / 32, LL), tb, 0, stream>>>(W1, W1T, DD, FF);
  tcast_kernel<<<dim3(DD / 32, FF / 32, LL), tb, 0, stream>>>(W2, W2T, FF, DD);
  // --- hs0/hs1 -> bf16 ---
  cast2_kernel<<<(BB * SS * DD / 4) / 256, 256, 0, stream>>>(hs0, hs1, hsb, hsb + (size_t)BB * SS * DD);
  // --- pooling + zero_indic -> q ---
  pool_kernel<<<dim3(BB * II, 3), 256, 0, stream>>>(hs0, mask, zib, qf, qb);

  for (int l = 0; l < LL; ++l) {
    const unsigned short* hsl = hsb + (size_t)l * BB * SS * DD;
    // fused K, V projections (M=2048 each -> 128^2 tiles, grid 192 blocks)
    GB gK = { hsl, WkT + (size_t)l * DD * DD, bk + l * DD, khb, BB * SS };
    GB gV = { hsl, WvT + (size_t)l * DD * DD, bv + l * DD, vhb, BB * SS };
    gemm_nt<0, 0><<<dim3(16, 6, 2), 256, 0, stream>>>(gK, gV, gK, DD, DD);
    // Q projection (M=256 -> 64^2 tiles, 48 blocks)
    GB gQ = { qb, WqT + (size_t)l * DD * DD, bq + l * DD, qhb, BB * II };
    gemm_nt64<0, 0><<<dim3(4, 12), 256, 0, stream>>>(gQ, DD, DD);
    // attention
    attn_kernel<<<dim3(BB * HH, 4), 256, 0, stream>>>(qhb, khb, vhb, mask, zib, ctxb);
    // Wo projection
    GB gO = { ctxb, WoT + (size_t)l * DD * DD, bo + l * DD, att_o, BB * II };
    gemm_nt64<0, 0><<<dim3(4, 12), 256, 0, stream>>>(gO, DD, DD);
    // LN1 (residual q + att_o)
    ln_kernel<<<BB * II, 256, 0, stream>>>(qf, att_o, ln1g + l * DD, ln1b + l * DD, qf, qb);
    // FFN1 (GELU, bf16 out)
    GB gF1 = { qb, W1T + (size_t)l * FF * DD, b1 + l * FF, ffh, BB * II };
    gemm_nt64<1, 1><<<dim3(4, FF / 64), 256, 0, stream>>>(gF1, FF, DD);
    // FFN2
    GB gF2 = { ffh, W2T + (size_t)l * DD * FF, b2 + l * DD, ffo, BB * II };
    gemm_nt64<0, 0><<<dim3(4, 12), 256, 0, stream>>>(gF2, DD, FF);
    // LN2
    ln_kernel<<<BB * II, 256, 0, stream>>>(qf, ffo, ln2g + l * DD, ln2b + l * DD, qf, qb);
  }
  // final substitution
  final_kernel<<<(BB * II * DD) / 256, 256, 0, stream>>>(qf, zib, zc, (float*)d_out);
}

// Round 3
// 272.009 us; speedup vs baseline: 1.9756x; 1.3982x over previous
//
#include <hip/hip_runtime.h>
#include <hip/hip_bf16.h>
#include <math.h>

#define BB 4
#define SS 512
#define DD 768
#define II 64
#define LL 2
#define HH 12
#define FF 3072

using short8 = __attribute__((ext_vector_type(8))) short;
using f32x4  = __attribute__((ext_vector_type(4))) float;

__device__ __forceinline__ unsigned short f2bf(float x) {
  return __builtin_bit_cast(unsigned short, __float2bfloat16(x));
}

__device__ __forceinline__ void gload_lds16(const void* g, void* l) {
  __builtin_amdgcn_global_load_lds((const __attribute__((address_space(1))) unsigned int*)g,
                                   (__attribute__((address_space(3))) unsigned int*)l, 16, 0, 0);
}

// ---------------- cast hs0/hs1 to bf16 ----------------
__global__ __launch_bounds__(256) void cast2_kernel(const float* __restrict__ a, const float* __restrict__ b,
                                                    unsigned short* __restrict__ oa, unsigned short* __restrict__ ob) {
  int idx = blockIdx.x * 256 + threadIdx.x;
  float4 va = ((const float4*)a)[idx];
  float4 vb = ((const float4*)b)[idx];
  union { unsigned short u[4]; uint2 v; } pa, pb;
  pa.u[0] = f2bf(va.x); pa.u[1] = f2bf(va.y); pa.u[2] = f2bf(va.z); pa.u[3] = f2bf(va.w);
  pb.u[0] = f2bf(vb.x); pb.u[1] = f2bf(vb.y); pb.u[2] = f2bf(vb.z); pb.u[3] = f2bf(vb.w);
  ((uint2*)oa)[idx] = pa.v;
  ((uint2*)ob)[idx] = pb.v;
}

// ---------------- batched transpose+cast for the 4 square weights ----------------
struct T4 { const float* s[4]; };

__global__ __launch_bounds__(256) void tcast4_kernel(T4 src, unsigned short* __restrict__ dst) {
  __shared__ float tile[32][33];
  int z = blockIdx.z;              // widx*LL + l
  int widx = z >> 1, l = z & 1;
  const float* Ws = src.s[widx] + (size_t)l * DD * DD;
  unsigned short* WTs = dst + ((size_t)widx * LL + l) * DD * DD;
  int n0 = blockIdx.x * 32, k0 = blockIdx.y * 32;
  int tx = threadIdx.x, ty = threadIdx.y;  // (32,8)
  #pragma unroll
  for (int r = 0; r < 4; ++r) tile[ty + 8 * r][tx] = Ws[(size_t)(k0 + ty + 8 * r) * DD + (n0 + tx)];
  __syncthreads();
  #pragma unroll
  for (int r = 0; r < 4; ++r) WTs[(size_t)(n0 + ty + 8 * r) * DD + (k0 + tx)] = f2bf(tile[tx][ty + 8 * r]);
}

// ---------------- transpose + cast: W[l][K][N] f32 -> WT[l][N][K] bf16 ----------------
__global__ __launch_bounds__(256) void tcast_kernel(const float* __restrict__ W, unsigned short* __restrict__ WT,
                                                    int K, int N) {
  __shared__ float tile[32][33];
  int l = blockIdx.z;
  const float* Ws = W + (size_t)l * K * N;
  unsigned short* WTs = WT + (size_t)l * N * K;
  int n0 = blockIdx.x * 32, k0 = blockIdx.y * 32;
  int tx = threadIdx.x, ty = threadIdx.y;  // (32,8)
  #pragma unroll
  for (int r = 0; r < 4; ++r) tile[ty + 8 * r][tx] = Ws[(size_t)(k0 + ty + 8 * r) * N + (n0 + tx)];
  __syncthreads();
  #pragma unroll
  for (int r = 0; r < 4; ++r) WTs[(size_t)(n0 + ty + 8 * r) * K + (k0 + tx)] = f2bf(tile[tx][ty + 8 * r]);
}

// ---------------- per-head V transpose: vhb[B*S][D](bf16) -> vT[bh][64][S](bf16) ----------------
__global__ __launch_bounds__(256) void vt_kernel(const unsigned short* __restrict__ vhb,
                                                 unsigned short* __restrict__ vT) {
  __shared__ unsigned short tile[32][33];
  int bh = blockIdx.z;
  int b = bh / HH, h = bh - b * HH;
  int s0 = blockIdx.x * 32, d0 = blockIdx.y * 32;
  int tx = threadIdx.x, ty = threadIdx.y;  // (32,8)
  const unsigned short* src = vhb + (size_t)(b * SS + s0) * DD + h * 64 + d0;
  #pragma unroll
  for (int r = 0; r < 4; ++r) tile[ty + 8 * r][tx] = src[(size_t)(ty + 8 * r) * DD + tx];
  __syncthreads();
  unsigned short* dst = vT + ((size_t)bh * 64 + d0) * SS + s0;
  #pragma unroll
  for (int r = 0; r < 4; ++r) dst[(size_t)(ty + 8 * r) * SS + tx] = tile[tx][ty + 8 * r];
}

// ---------------- masked max pooling + zero_indic + ext buffer ----------------
__global__ __launch_bounds__(256) void pool_kernel(const float* __restrict__ hs0, const int* __restrict__ mask,
                                                   int* __restrict__ zi, float* __restrict__ qf,
                                                   unsigned short* __restrict__ qb, float* __restrict__ extf) {
  __shared__ float eadd[SS];
  int bi = blockIdx.x;  // b*II + i
  int b = bi >> 6, dz = blockIdx.y, t = threadIdx.x;
  const int* mrow = mask + (size_t)bi * SS;
  int incl = 0;
  for (int s = t; s < SS; s += 256) {
    int m = mrow[s];
    eadd[s] = m ? -__builtin_inff() : 0.0f;
    incl |= (m == 0);
  }
  int any = __syncthreads_or(incl);
  int z = !any;
  if (dz == 0) {
    if (t == 0) zi[bi] = z;
    for (int s = t; s < SS; s += 256)
      extf[(size_t)bi * SS + s] = (z || eadd[s] == 0.0f) ? 0.0f : -10000.0f;
  }
  const float* hb = hs0 + (size_t)b * SS * DD + dz * 256 + t;
  float m[8];
  #pragma unroll
  for (int j = 0; j < 8; ++j) m[j] = -3.4e38f;
  for (int s0 = 0; s0 < SS; s0 += 8) {
    #pragma unroll
    for (int j = 0; j < 8; ++j)
      m[j] = fmaxf(m[j], hb[(size_t)(s0 + j) * DD] + eadd[s0 + j]);
  }
  float mm = fmaxf(fmaxf(fmaxf(m[0], m[1]), fmaxf(m[2], m[3])),
                   fmaxf(fmaxf(m[4], m[5]), fmaxf(m[6], m[7])));
  size_t o = (size_t)bi * DD + dz * 256 + t;
  qf[o] = mm;
  qb[o] = f2bf(mm);
}

// ---------------- NT GEMM 128x128 ----------------
struct GB { const unsigned short* A; const unsigned short* Bt; const float* bias; void* C; int M; };

template <int GELU, int OUTBF>
__global__ __launch_bounds__(256) void gemm_nt(GB g0, GB g1, GB g2, int N, int K) {
  __shared__ unsigned short Al[128 * 64];
  __shared__ unsigned short Bl[128 * 64];
  GB g = (blockIdx.z == 0) ? g0 : (blockIdx.z == 1 ? g1 : g2);
  int bm = blockIdx.x, bn = blockIdx.y;
  if (bm * 128 >= g.M) return;
  int t = threadIdx.x, w = t >> 6, lane = t & 63;
  int hi = lane >> 4, lo = lane & 15;
  int wr = w >> 1, wc = w & 1;
  f32x4 acc[4][4] = {};
  const char* Abase = (const char*)g.A + (size_t)(bm * 128) * (size_t)K * 2;
  const char* Bbase = (const char*)g.Bt + (size_t)(bn * 128) * (size_t)K * 2;
  int rowbytes = K * 2;
  int KT = K >> 6;
  for (int kt = 0; kt < KT; ++kt) {
    int k0b = kt * 128;
    #pragma unroll
    for (int c = 0; c < 4; ++c) {
      int base = (c * 4 + w) << 10;
      int o = base + lane * 16;
      int row = o >> 7, cb = o & 127;
      int scb = cb ^ ((row & 7) << 4);
      gload_lds16(Abase + (size_t)row * rowbytes + (k0b + scb), (char*)Al + base);
      gload_lds16(Bbase + (size_t)row * rowbytes + (k0b + scb), (char*)Bl + base);
    }
    __syncthreads();
    #pragma unroll
    for (int kk = 0; kk < 2; ++kk) {
      short8 av[4], bv_[4];
      #pragma unroll
      for (int mi = 0; mi < 4; ++mi) {
        int r = wr * 64 + mi * 16 + lo;
        av[mi] = *(const short8*)((const char*)Al + r * 128 + ((kk * 64 + hi * 16) ^ ((r & 7) << 4)));
      }
      #pragma unroll
      for (int ni = 0; ni < 4; ++ni) {
        int r = wc * 64 + ni * 16 + lo;
        bv_[ni] = *(const short8*)((const char*)Bl + r * 128 + ((kk * 64 + hi * 16) ^ ((r & 7) << 4)));
      }
      #pragma unroll
      for (int mi = 0; mi < 4; ++mi)
        #pragma unroll
        for (int ni = 0; ni < 4; ++ni)
          acc[mi][ni] = __builtin_amdgcn_mfma_f32_16x16x32_bf16(av[mi], bv_[ni], acc[mi][ni], 0, 0, 0);
    }
    __syncthreads();
  }
  int mbase = bm * 128 + wr * 64;
  int nbase = bn * 128 + wc * 64;
  #pragma unroll
  for (int mi = 0; mi < 4; ++mi)
    #pragma unroll
    for (int ni = 0; ni < 4; ++ni)
      #pragma unroll
      for (int r = 0; r < 4; ++r) {
        int gm = mbase + mi * 16 + hi * 4 + r;
        int gn = nbase + ni * 16 + lo;
        float v = acc[mi][ni][r] + g.bias[gn];
        if (GELU) v = 0.5f * v * (1.0f + erff(v * 0.70710678118654752f));
        if (OUTBF) ((unsigned short*)g.C)[(size_t)gm * N + gn] = f2bf(v);
        else       ((float*)g.C)[(size_t)gm * N + gn] = v;
      }
}

// ---------------- NT GEMM 64x64 ----------------
template <int GELU, int OUTBF>
__global__ __launch_bounds__(256) void gemm_nt64(GB g, int N, int K) {
  __shared__ unsigned short Al[64 * 64];
  __shared__ unsigned short Bl[64 * 64];
  int bm = blockIdx.x, bn = blockIdx.y;
  int t = threadIdx.x, w = t >> 6, lane = t & 63;
  int hi = lane >> 4, lo = lane & 15;
  int wr = w >> 1, wc = w & 1;
  f32x4 acc[2][2] = {};
  const char* Abase = (const char*)g.A + (size_t)(bm * 64) * (size_t)K * 2;
  const char* Bbase = (const char*)g.Bt + (size_t)(bn * 64) * (size_t)K * 2;
  int rowbytes = K * 2;
  int KT = K >> 6;
  for (int kt = 0; kt < KT; ++kt) {
    int k0b = kt * 128;
    #pragma unroll
    for (int c = 0; c < 2; ++c) {
      int base = (c * 4 + w) << 10;
      int o = base + lane * 16;
      int row = o >> 7, cb = o & 127;
      int scb = cb ^ ((row & 7) << 4);
      gload_lds16(Abase + (size_t)row * rowbytes + (k0b + scb), (char*)Al + base);
      gload_lds16(Bbase + (size_t)row * rowbytes + (k0b + scb), (char*)Bl + base);
    }
    __syncthreads();
    #pragma unroll
    for (int kk = 0; kk < 2; ++kk) {
      short8 av[2], bv_[2];
      #pragma unroll
      for (int mi = 0; mi < 2; ++mi) {
        int r = wr * 32 + mi * 16 + lo;
        av[mi] = *(const short8*)((const char*)Al + r * 128 + ((kk * 64 + hi * 16) ^ ((r & 7) << 4)));
      }
      #pragma unroll
      for (int ni = 0; ni < 2; ++ni) {
        int r = wc * 32 + ni * 16 + lo;
        bv_[ni] = *(const short8*)((const char*)Bl + r * 128 + ((kk * 64 + hi * 16) ^ ((r & 7) << 4)));
      }
      #pragma unroll
      for (int mi = 0; mi < 2; ++mi)
        #pragma unroll
        for (int ni = 0; ni < 2; ++ni)
          acc[mi][ni] = __builtin_amdgcn_mfma_f32_16x16x32_bf16(av[mi], bv_[ni], acc[mi][ni], 0, 0, 0);
    }
    __syncthreads();
  }
  int mbase = bm * 64 + wr * 32;
  int nbase = bn * 64 + wc * 32;
  #pragma unroll
  for (int mi = 0; mi < 2; ++mi)
    #pragma unroll
    for (int ni = 0; ni < 2; ++ni)
      #pragma unroll
      for (int r = 0; r < 4; ++r) {
        int gm = mbase + mi * 16 + hi * 4 + r;
        int gn = nbase + ni * 16 + lo;
        float v = acc[mi][ni][r] + g.bias[gn];
        if (GELU) v = 0.5f * v * (1.0f + erff(v * 0.70710678118654752f));
        if (OUTBF) ((unsigned short*)g.C)[(size_t)gm * N + gn] = f2bf(v);
        else       ((float*)g.C)[(size_t)gm * N + gn] = v;
      }
}

// ---------------- QK^T: scores[bh][64][S] = Qh*Kh^T*0.125 + ext ----------------
__global__ __launch_bounds__(256) void qk_kernel(const unsigned short* __restrict__ qhb,
                                                 const unsigned short* __restrict__ khb,
                                                 const float* __restrict__ extf,
                                                 float* __restrict__ sbuf) {
  __shared__ unsigned short Al[64 * 64];    // 8 KB
  __shared__ unsigned short Bl[128 * 64];   // 16 KB
  int bh = blockIdx.x;
  int b = bh / HH, h = bh - b * HH;
  int s0 = blockIdx.y * 128;
  int t = threadIdx.x, w = t >> 6, lane = t & 63;
  int hi = lane >> 4, lo = lane & 15;
  const char* Ab = (const char*)(qhb + (size_t)(b * II) * DD + h * 64);
  const char* Bb = (const char*)(khb + (size_t)(b * SS + s0) * DD + h * 64);
  #pragma unroll
  for (int c = 0; c < 2; ++c) {
    int base = (c * 4 + w) << 10;
    int o = base + lane * 16;
    int row = o >> 7, cb = o & 127;
    int scb = cb ^ ((row & 7) << 4);
    gload_lds16(Ab + (size_t)row * (DD * 2) + scb, (char*)Al + base);
  }
  #pragma unroll
  for (int c = 0; c < 4; ++c) {
    int base = (c * 4 + w) << 10;
    int o = base + lane * 16;
    int row = o >> 7, cb = o & 127;
    int scb = cb ^ ((row & 7) << 4);
    gload_lds16(Bb + (size_t)row * (DD * 2) + scb, (char*)Bl + base);
  }
  __syncthreads();
  f32x4 acc[4][2] = {};
  #pragma unroll
  for (int kk = 0; kk < 2; ++kk) {
    short8 av[4], bv_[2];
    #pragma unroll
    for (int mi = 0; mi < 4; ++mi) {
      int r = mi * 16 + lo;
      av[mi] = *(const short8*)((const char*)Al + r * 128 + ((kk * 64 + hi * 16) ^ ((r & 7) << 4)));
    }
    #pragma unroll
    for (int ni = 0; ni < 2; ++ni) {
      int r = w * 32 + ni * 16 + lo;
      bv_[ni] = *(const short8*)((const char*)Bl + r * 128 + ((kk * 64 + hi * 16) ^ ((r & 7) << 4)));
    }
    #pragma unroll
    for (int mi = 0; mi < 4; ++mi)
      #pragma unroll
      for (int ni = 0; ni < 2; ++ni)
        acc[mi][ni] = __builtin_amdgcn_mfma_f32_16x16x32_bf16(av[mi], bv_[ni], acc[mi][ni], 0, 0, 0);
  }
  float* srow = sbuf + (size_t)bh * II * SS;
  #pragma unroll
  for (int mi = 0; mi < 4; ++mi)
    #pragma unroll
    for (int ni = 0; ni < 2; ++ni)
      #pragma unroll
      for (int r = 0; r < 4; ++r) {
        int gm = mi * 16 + hi * 4 + r;
        int gn = w * 32 + ni * 16 + lo;
        float ext = extf[(size_t)(b * II + gm) * SS + s0 + gn];
        srow[(size_t)gm * SS + s0 + gn] = acc[mi][ni][r] * 0.125f + ext;
      }
}

// ---------------- row softmax: sbuf fp32 -> pb bf16 (normalized) ----------------
__global__ __launch_bounds__(256) void sm_kernel(const float* __restrict__ sbuf,
                                                 unsigned short* __restrict__ pb) {
  int t = threadIdx.x, w = t >> 6, l = t & 63;
  int row = blockIdx.x * 4 + w;  // 3072 rows
  const float* rp = sbuf + (size_t)row * SS + l * 8;
  float4 v0 = *(const float4*)rp;
  float4 v1 = *(const float4*)(rp + 4);
  float mx = fmaxf(fmaxf(fmaxf(v0.x, v0.y), fmaxf(v0.z, v0.w)),
                   fmaxf(fmaxf(v1.x, v1.y), fmaxf(v1.z, v1.w)));
  #pragma unroll
  for (int o2 = 32; o2; o2 >>= 1) mx = fmaxf(mx, __shfl_xor(mx, o2));
  float e[8];
  e[0] = __expf(v0.x - mx); e[1] = __expf(v0.y - mx); e[2] = __expf(v0.z - mx); e[3] = __expf(v0.w - mx);
  e[4] = __expf(v1.x - mx); e[5] = __expf(v1.y - mx); e[6] = __expf(v1.z - mx); e[7] = __expf(v1.w - mx);
  float sum = ((e[0] + e[1]) + (e[2] + e[3])) + ((e[4] + e[5]) + (e[6] + e[7]));
  #pragma unroll
  for (int o2 = 32; o2; o2 >>= 1) sum += __shfl_xor(sum, o2);
  float rinv = 1.0f / sum;
  short8 out;
  #pragma unroll
  for (int j = 0; j < 8; ++j) out[j] = (short)f2bf(e[j] * rinv);
  *(short8*)(pb + (size_t)row * SS + l * 8) = out;
}

// ---------------- PV: ctx[b*64+i][h*64+dh] = P[bh] @ vT[bh]^T ----------------
__global__ __launch_bounds__(256) void pv_kernel(const unsigned short* __restrict__ pb,
                                                 const unsigned short* __restrict__ vT,
                                                 unsigned short* __restrict__ ctx) {
  __shared__ unsigned short Al[64 * 64];
  __shared__ unsigned short Bl[64 * 64];
  int bh = blockIdx.x;
  int b = bh / HH, h = bh - b * HH;
  int t = threadIdx.x, w = t >> 6, lane = t & 63;
  int hi = lane >> 4, lo = lane & 15;
  int wr = w >> 1, wc = w & 1;
  f32x4 acc[2][2] = {};
  const char* Abase = (const char*)(pb + (size_t)bh * II * SS);
  const char* Bbase = (const char*)(vT + (size_t)bh * 64 * SS);
  for (int kt = 0; kt < 8; ++kt) {
    int k0b = kt * 128;
    #pragma unroll
    for (int c = 0; c < 2; ++c) {
      int base = (c * 4 + w) << 10;
      int o = base + lane * 16;
      int row = o >> 7, cb = o & 127;
      int scb = cb ^ ((row & 7) << 4);
      gload_lds16(Abase + (size_t)row * (SS * 2) + k0b + scb, (char*)Al + base);
      gload_lds16(Bbase + (size_t)row * (SS * 2) + k0b + scb, (char*)Bl + base);
    }
    __syncthreads();
    #pragma unroll
    for (int kk = 0; kk < 2; ++kk) {
      short8 av[2], bv_[2];
      #pragma unroll
      for (int mi = 0; mi < 2; ++mi) {
        int r = wr * 32 + mi * 16 + lo;
        av[mi] = *(const short8*)((const char*)Al + r * 128 + ((kk * 64 + hi * 16) ^ ((r & 7) << 4)));
      }
      #pragma unroll
      for (int ni = 0; ni < 2; ++ni) {
        int r = wc * 32 + ni * 16 + lo;
        bv_[ni] = *(const short8*)((const char*)Bl + r * 128 + ((kk * 64 + hi * 16) ^ ((r & 7) << 4)));
      }
      #pragma unroll
      for (int mi = 0; mi < 2; ++mi)
        #pragma unroll
        for (int ni = 0; ni < 2; ++ni)
          acc[mi][ni] = __builtin_amdgcn_mfma_f32_16x16x32_bf16(av[mi], bv_[ni], acc[mi][ni], 0, 0, 0);
    }
    __syncthreads();
  }
  #pragma unroll
  for (int mi = 0; mi < 2; ++mi)
    #pragma unroll
    for (int ni = 0; ni < 2; ++ni)
      #pragma unroll
      for (int r = 0; r < 4; ++r) {
        int gm = wr * 32 + mi * 16 + hi * 4 + r;
        int gn = wc * 32 + ni * 16 + lo;
        ctx[(size_t)(b * II + gm) * DD + h * 64 + gn] = f2bf(acc[mi][ni][r]);
      }
}

// ---------------- residual + LayerNorm ----------------
__global__ __launch_bounds__(256) void ln_kernel(const float* __restrict__ x, const float* __restrict__ y,
                                                 const float* __restrict__ g, const float* __restrict__ bb,
                                                 float* __restrict__ qf, unsigned short* __restrict__ qb) {
  __shared__ float r1[4], r2[4];
  int r = blockIdx.x, t = threadIdx.x;
  size_t o = (size_t)r * DD;
  float v0 = x[o + t] + y[o + t];
  float v1 = x[o + t + 256] + y[o + t + 256];
  float v2 = x[o + t + 512] + y[o + t + 512];
  float s = v0 + v1 + v2, ss = v0 * v0 + v1 * v1 + v2 * v2;
  #pragma unroll
  for (int o2 = 32; o2; o2 >>= 1) { s += __shfl_xor(s, o2); ss += __shfl_xor(ss, o2); }
  if ((t & 63) == 0) { r1[t >> 6] = s; r2[t >> 6] = ss; }
  __syncthreads();
  s = r1[0] + r1[1] + r1[2] + r1[3];
  ss = r2[0] + r2[1] + r2[2] + r2[3];
  float mean = s * (1.0f / DD);
  float var = ss * (1.0f / DD) - mean * mean;
  float inv = rsqrtf(var + 1e-12f);
  float w0 = (v0 - mean) * inv * g[t] + bb[t];
  float w1 = (v1 - mean) * inv * g[t + 256] + bb[t + 256];
  float w2 = (v2 - mean) * inv * g[t + 512] + bb[t + 512];
  qf[o + t] = w0; qf[o + t + 256] = w1; qf[o + t + 512] = w2;
  qb[o + t] = f2bf(w0); qb[o + t + 256] = f2bf(w1); qb[o + t + 512] = f2bf(w2);
}

// ---------------- final zero-context substitution ----------------
__global__ __launch_bounds__(256) void final_kernel(const float* __restrict__ q, const int* __restrict__ zi,
                                                    const float* __restrict__ zc, float* __restrict__ out) {
  int idx = blockIdx.x * 256 + threadIdx.x;
  int bi = idx / DD, d = idx - bi * DD;
  out[idx] = zi[bi] ? zc[d] : q[idx];
}

extern "C" void kernel_launch(void* const* d_in, const int* in_sizes, int n_in,
                              void* d_out, int out_size, void* d_ws, size_t ws_size,
                              hipStream_t stream) {
  (void)in_sizes; (void)n_in; (void)out_size; (void)ws_size;
  const float* hs0 = (const float*)d_in[0];
  const float* hs1 = (const float*)d_in[1];
  const float* Wq  = (const float*)d_in[3];
  const float* bq  = (const float*)d_in[4];
  const float* Wk  = (const float*)d_in[5];
  const float* bk  = (const float*)d_in[6];
  const float* Wv  = (const float*)d_in[7];
  const float* bv  = (const float*)d_in[8];
  const float* Wo  = (const float*)d_in[9];
  const float* bo  = (const float*)d_in[10];
  const float* ln1g = (const float*)d_in[11];
  const float* ln1b = (const float*)d_in[12];
  const float* W1  = (const float*)d_in[13];
  const float* b1  = (const float*)d_in[14];
  const float* W2  = (const float*)d_in[15];
  const float* b2  = (const float*)d_in[16];
  const float* ln2g = (const float*)d_in[17];
  const float* ln2b = (const float*)d_in[18];
  const float* zc  = (const float*)d_in[19];
  const int*   mask = (const int*)d_in[20];

  char* ws = (char*)d_ws;
  size_t off = 0;
  auto alloc = [&](size_t bytes) { size_t o = off; off += (bytes + 255) & ~(size_t)255; return o; };

  unsigned short* WT4 = (unsigned short*)(ws + alloc((size_t)4 * LL * DD * DD * 2));
  unsigned short* W1T = (unsigned short*)(ws + alloc((size_t)LL * FF * DD * 2));
  unsigned short* W2T = (unsigned short*)(ws + alloc((size_t)LL * DD * FF * 2));
  unsigned short* hsb = (unsigned short*)(ws + alloc((size_t)2 * BB * SS * DD * 2));
  float*          qf  = (float*)(ws + alloc((size_t)BB * II * DD * 4));
  unsigned short* qb  = (unsigned short*)(ws + alloc((size_t)BB * II * DD * 2));
  unsigned short* qhb = (unsigned short*)(ws + alloc((size_t)BB * II * DD * 2));
  unsigned short* khb = (unsigned short*)(ws + alloc((size_t)BB * SS * DD * 2));
  unsigned short* vhb = (unsigned short*)(ws + alloc((size_t)BB * SS * DD * 2));
  unsigned short* vTb = (unsigned short*)(ws + alloc((size_t)BB * HH * 64 * SS * 2));
  float*          sbuf = (float*)(ws + alloc((size_t)BB * HH * II * SS * 4));
  unsigned short* pbuf = (unsigned short*)(ws + alloc((size_t)BB * HH * II * SS * 2));
  unsigned short* ctxb = (unsigned short*)(ws + alloc((size_t)BB * II * DD * 2));
  float*          att_o = (float*)(ws + alloc((size_t)BB * II * DD * 4));
  unsigned short* ffh = (unsigned short*)(ws + alloc((size_t)BB * II * FF * 2));
  float*          ffo = (float*)(ws + alloc((size_t)BB * II * DD * 4));
  float*          extf = (float*)(ws + alloc((size_t)BB * II * SS * 4));
  int*            zib = (int*)(ws + alloc((size_t)BB * II * 4));

  unsigned short* WqT = WT4 + 0 * (size_t)LL * DD * DD;
  unsigned short* WkT = WT4 + 1 * (size_t)LL * DD * DD;
  unsigned short* WvT = WT4 + 2 * (size_t)LL * DD * DD;
  unsigned short* WoT = WT4 + 3 * (size_t)LL * DD * DD;

  dim3 tb(32, 8);
  T4 t4 = { { Wq, Wk, Wv, Wo } };
  tcast4_kernel<<<dim3(DD / 32, DD / 32, 4 * LL), tb, 0, stream>>>(t4, WT4);
  tcast_kernel<<<dim3(FF / 32, DD / 32, LL), tb, 0, stream>>>(W1, W1T, DD, FF);
  tcast_kernel<<<dim3(DD / 32, FF / 32, LL), tb, 0, stream>>>(W2, W2T, FF, DD);
  cast2_kernel<<<(BB * SS * DD / 4) / 256, 256, 0, stream>>>(hs0, hs1, hsb, hsb + (size_t)BB * SS * DD);
  pool_kernel<<<dim3(BB * II, 3), 256, 0, stream>>>(hs0, mask, zib, qf, qb, extf);

  for (int l = 0; l < LL; ++l) {
    const unsigned short* hsl = hsb + (size_t)l * BB * SS * DD;
    // K, V projections -> bf16
    GB gK = { hsl, WkT + (size_t)l * DD * DD, bk + l * DD, khb, BB * SS };
    GB gV = { hsl, WvT + (size_t)l * DD * DD, bv + l * DD, vhb, BB * SS };
    gemm_nt<0, 1><<<dim3(16, 6, 2), 256, 0, stream>>>(gK, gV, gK, DD, DD);
    // per-head V transpose
    vt_kernel<<<dim3(SS / 32, 2, BB * HH), tb, 0, stream>>>(vhb, vTb);
    // Q projection -> bf16
    GB gQ = { qb, WqT + (size_t)l * DD * DD, bq + l * DD, qhb, BB * II };
    gemm_nt64<0, 1><<<dim3(4, 12), 256, 0, stream>>>(gQ, DD, DD);
    // QK^T + mask
    qk_kernel<<<dim3(BB * HH, 4), 256, 0, stream>>>(qhb, khb, extf, sbuf);
    // softmax
    sm_kernel<<<BB * HH * II / 4, 256, 0, stream>>>(sbuf, pbuf);
    // PV
    pv_kernel<<<BB * HH, 256, 0, stream>>>(pbuf, vTb, ctxb);
    // Wo projection
    GB gO = { ctxb, WoT + (size_t)l * DD * DD, bo + l * DD, att_o, BB * II };
    gemm_nt64<0, 0><<<dim3(4, 12), 256, 0, stream>>>(gO, DD, DD);
    // LN1
    ln_kernel<<<BB * II, 256, 0, stream>>>(qf, att_o, ln1g + l * DD, ln1b + l * DD, qf, qb);
    // FFN1 (GELU, bf16 out)
    GB gF1 = { qb, W1T + (size_t)l * FF * DD, b1 + l * FF, ffh, BB * II };
    gemm_nt64<1, 1><<<dim3(4, FF / 64), 256, 0, stream>>>(gF1, FF, DD);
    // FFN2
    GB gF2 = { ffh, W2T + (size_t)l * DD * FF, b2 + l * DD, ffo, BB * II };
    gemm_nt64<0, 0><<<dim3(4, 12), 256, 0, stream>>>(gF2, DD, FF);
    // LN2
    ln_kernel<<<BB * II, 256, 0, stream>>>(qf, ffo, ln2g + l * DD, ln2b + l * DD, qf, qb);
  }
  final_kernel<<<(BB * II * DD) / 256, 256, 0, stream>>>(qf, zib, zc, (float*)d_out);
}

// Round 4
// 254.416 us; speedup vs baseline: 2.1122x; 1.0692x over previous
//
#include <hip/hip_runtime.h>
#include <hip/hip_bf16.h>
#include <math.h>

#define BB 4
#define SS 512
#define DD 768
#define II 64
#define LL 2
#define HH 12
#define FF 3072

using short8 = __attribute__((ext_vector_type(8))) short;
using f32x4  = __attribute__((ext_vector_type(4))) float;

__device__ __forceinline__ unsigned short f2bf(float x) {
  return __builtin_bit_cast(unsigned short, __float2bfloat16(x));
}

__device__ __forceinline__ void gload_lds16(const void* g, void* l) {
  __builtin_amdgcn_global_load_lds((const __attribute__((address_space(1))) unsigned int*)g,
                                   (__attribute__((address_space(3))) unsigned int*)l, 16, 0, 0);
}

// ---------------- cast hs0/hs1 to bf16 ----------------
__global__ __launch_bounds__(256) void cast2_kernel(const float* __restrict__ a, const float* __restrict__ b,
                                                    unsigned short* __restrict__ oa, unsigned short* __restrict__ ob) {
  int idx = blockIdx.x * 256 + threadIdx.x;
  float4 va = ((const float4*)a)[idx];
  float4 vb = ((const float4*)b)[idx];
  union { unsigned short u[4]; uint2 v; } pa, pb;
  pa.u[0] = f2bf(va.x); pa.u[1] = f2bf(va.y); pa.u[2] = f2bf(va.z); pa.u[3] = f2bf(va.w);
  pb.u[0] = f2bf(vb.x); pb.u[1] = f2bf(vb.y); pb.u[2] = f2bf(vb.z); pb.u[3] = f2bf(vb.w);
  ((uint2*)oa)[idx] = pa.v;
  ((uint2*)ob)[idx] = pb.v;
}

// ---------------- batched transpose+cast for the 4 square weights ----------------
struct T4 { const float* s[4]; };

__global__ __launch_bounds__(256) void tcast4_kernel(T4 src, unsigned short* __restrict__ dst) {
  __shared__ float tile[32][33];
  int z = blockIdx.z;              // widx*LL + l
  int widx = z >> 1, l = z & 1;
  const float* Ws = src.s[widx] + (size_t)l * DD * DD;
  unsigned short* WTs = dst + ((size_t)widx * LL + l) * DD * DD;
  int n0 = blockIdx.x * 32, k0 = blockIdx.y * 32;
  int tx = threadIdx.x, ty = threadIdx.y;  // (32,8)
  #pragma unroll
  for (int r = 0; r < 4; ++r) tile[ty + 8 * r][tx] = Ws[(size_t)(k0 + ty + 8 * r) * DD + (n0 + tx)];
  __syncthreads();
  #pragma unroll
  for (int r = 0; r < 4; ++r) WTs[(size_t)(n0 + ty + 8 * r) * DD + (k0 + tx)] = f2bf(tile[tx][ty + 8 * r]);
}

// ---------------- transpose + cast: W[l][K][N] f32 -> WT[l][N][K] bf16 ----------------
__global__ __launch_bounds__(256) void tcast_kernel(const float* __restrict__ W, unsigned short* __restrict__ WT,
                                                    int K, int N) {
  __shared__ float tile[32][33];
  int l = blockIdx.z;
  const float* Ws = W + (size_t)l * K * N;
  unsigned short* WTs = WT + (size_t)l * N * K;
  int n0 = blockIdx.x * 32, k0 = blockIdx.y * 32;
  int tx = threadIdx.x, ty = threadIdx.y;  // (32,8)
  #pragma unroll
  for (int r = 0; r < 4; ++r) tile[ty + 8 * r][tx] = Ws[(size_t)(k0 + ty + 8 * r) * N + (n0 + tx)];
  __syncthreads();
  #pragma unroll
  for (int r = 0; r < 4; ++r) WTs[(size_t)(n0 + ty + 8 * r) * K + (k0 + tx)] = f2bf(tile[tx][ty + 8 * r]);
}

// ---------------- masked max pooling + zero_indic + bit-packed inclusion mask ----------------
__global__ __launch_bounds__(256) void pool_kernel(const float* __restrict__ hs0, const int* __restrict__ mask,
                                                   int* __restrict__ zi, float* __restrict__ qf,
                                                   unsigned short* __restrict__ qb,
                                                   unsigned long long* __restrict__ pmask) {
  __shared__ float eadd[SS];
  int bi = blockIdx.x;  // b*II + i
  int b = bi >> 6, dz = blockIdx.y, t = threadIdx.x, w = t >> 6;
  const int* mrow = mask + (size_t)bi * SS;
  int m0v = mrow[t], m1v = mrow[t + 256];
  eadd[t] = m0v ? -__builtin_inff() : 0.0f;
  eadd[t + 256] = m1v ? -__builtin_inff() : 0.0f;
  int incl = (m0v == 0) | (m1v == 0);
  int any = __syncthreads_or(incl);
  int z = !any;
  if (dz == 0) {
    unsigned long long w0 = __ballot(z || (m0v == 0));
    unsigned long long w1 = __ballot(z || (m1v == 0));
    if ((t & 63) == 0) {
      pmask[bi * 8 + w] = w0;
      pmask[bi * 8 + 4 + w] = w1;
      if (t == 0) zi[bi] = z;
    }
  }
  const float* hb = hs0 + (size_t)b * SS * DD + dz * 256 + t;
  float m[8];
  #pragma unroll
  for (int j = 0; j < 8; ++j) m[j] = -3.4e38f;
  for (int s0 = 0; s0 < SS; s0 += 8) {
    #pragma unroll
    for (int j = 0; j < 8; ++j)
      m[j] = fmaxf(m[j], hb[(size_t)(s0 + j) * DD] + eadd[s0 + j]);
  }
  float mm = fmaxf(fmaxf(fmaxf(m[0], m[1]), fmaxf(m[2], m[3])),
                   fmaxf(fmaxf(m[4], m[5]), fmaxf(m[6], m[7])));
  size_t o = (size_t)bi * DD + dz * 256 + t;
  qf[o] = mm;
  qb[o] = f2bf(mm);
}

// ---------------- NT GEMM 128x128 ----------------
struct GB { const unsigned short* A; const unsigned short* Bt; const float* bias; void* C;
            int M; int N; int rowbias; };

template <int GELU, int OUTBF>
__global__ __launch_bounds__(256) void gemm_nt(GB g0, GB g1, int K) {
  __shared__ unsigned short Al[128 * 64];
  __shared__ unsigned short Bl[128 * 64];
  GB g = blockIdx.z ? g1 : g0;
  int bm = blockIdx.x, bn = blockIdx.y;
  if (blockIdx.z) { bm = blockIdx.y; bn = blockIdx.x; }
  if (bm * 128 >= g.M) return;
  int t = threadIdx.x, w = t >> 6, lane = t & 63;
  int hi = lane >> 4, lo = lane & 15;
  int wr = w >> 1, wc = w & 1;
  f32x4 acc[4][4] = {};
  const char* Abase = (const char*)g.A + (size_t)(bm * 128) * (size_t)K * 2;
  const char* Bbase = (const char*)g.Bt + (size_t)(bn * 128) * (size_t)K * 2;
  int rowbytes = K * 2;
  int KT = K >> 6;
  for (int kt = 0; kt < KT; ++kt) {
    int k0b = kt * 128;
    #pragma unroll
    for (int c = 0; c < 4; ++c) {
      int base = (c * 4 + w) << 10;
      int o = base + lane * 16;
      int row = o >> 7, cb = o & 127;
      int scb = cb ^ ((row & 7) << 4);
      gload_lds16(Abase + (size_t)row * rowbytes + (k0b + scb), (char*)Al + base);
      gload_lds16(Bbase + (size_t)row * rowbytes + (k0b + scb), (char*)Bl + base);
    }
    __syncthreads();
    #pragma unroll
    for (int kk = 0; kk < 2; ++kk) {
      short8 av[4], bv_[4];
      #pragma unroll
      for (int mi = 0; mi < 4; ++mi) {
        int r = wr * 64 + mi * 16 + lo;
        av[mi] = *(const short8*)((const char*)Al + r * 128 + ((kk * 64 + hi * 16) ^ ((r & 7) << 4)));
      }
      #pragma unroll
      for (int ni = 0; ni < 4; ++ni) {
        int r = wc * 64 + ni * 16 + lo;
        bv_[ni] = *(const short8*)((const char*)Bl + r * 128 + ((kk * 64 + hi * 16) ^ ((r & 7) << 4)));
      }
      #pragma unroll
      for (int mi = 0; mi < 4; ++mi)
        #pragma unroll
        for (int ni = 0; ni < 4; ++ni)
          acc[mi][ni] = __builtin_amdgcn_mfma_f32_16x16x32_bf16(av[mi], bv_[ni], acc[mi][ni], 0, 0, 0);
    }
    __syncthreads();
  }
  int mbase = bm * 128 + wr * 64;
  int nbase = bn * 128 + wc * 64;
  #pragma unroll
  for (int mi = 0; mi < 4; ++mi)
    #pragma unroll
    for (int ni = 0; ni < 4; ++ni)
      #pragma unroll
      for (int r = 0; r < 4; ++r) {
        int gm = mbase + mi * 16 + hi * 4 + r;
        int gn = nbase + ni * 16 + lo;
        float v = acc[mi][ni][r] + (g.rowbias ? g.bias[gm] : g.bias[gn]);
        if (GELU) v = 0.5f * v * (1.0f + erff(v * 0.70710678118654752f));
        if (OUTBF) ((unsigned short*)g.C)[(size_t)gm * g.N + gn] = f2bf(v);
        else       ((float*)g.C)[(size_t)gm * g.N + gn] = v;
      }
}

// ---------------- NT GEMM 64x64 ----------------
template <int GELU, int OUTBF>
__global__ __launch_bounds__(256) void gemm_nt64(GB g, int K) {
  __shared__ unsigned short Al[64 * 64];
  __shared__ unsigned short Bl[64 * 64];
  int bm = blockIdx.x, bn = blockIdx.y;
  int t = threadIdx.x, w = t >> 6, lane = t & 63;
  int hi = lane >> 4, lo = lane & 15;
  int wr = w >> 1, wc = w & 1;
  f32x4 acc[2][2] = {};
  const char* Abase = (const char*)g.A + (size_t)(bm * 64) * (size_t)K * 2;
  const char* Bbase = (const char*)g.Bt + (size_t)(bn * 64) * (size_t)K * 2;
  int rowbytes = K * 2;
  int KT = K >> 6;
  for (int kt = 0; kt < KT; ++kt) {
    int k0b = kt * 128;
    #pragma unroll
    for (int c = 0; c < 2; ++c) {
      int base = (c * 4 + w) << 10;
      int o = base + lane * 16;
      int row = o >> 7, cb = o & 127;
      int scb = cb ^ ((row & 7) << 4);
      gload_lds16(Abase + (size_t)row * rowbytes + (k0b + scb), (char*)Al + base);
      gload_lds16(Bbase + (size_t)row * rowbytes + (k0b + scb), (char*)Bl + base);
    }
    __syncthreads();
    #pragma unroll
    for (int kk = 0; kk < 2; ++kk) {
      short8 av[2], bv_[2];
      #pragma unroll
      for (int mi = 0; mi < 2; ++mi) {
        int r = wr * 32 + mi * 16 + lo;
        av[mi] = *(const short8*)((const char*)Al + r * 128 + ((kk * 64 + hi * 16) ^ ((r & 7) << 4)));
      }
      #pragma unroll
      for (int ni = 0; ni < 2; ++ni) {
        int r = wc * 32 + ni * 16 + lo;
        bv_[ni] = *(const short8*)((const char*)Bl + r * 128 + ((kk * 64 + hi * 16) ^ ((r & 7) << 4)));
      }
      #pragma unroll
      for (int mi = 0; mi < 2; ++mi)
        #pragma unroll
        for (int ni = 0; ni < 2; ++ni)
          acc[mi][ni] = __builtin_amdgcn_mfma_f32_16x16x32_bf16(av[mi], bv_[ni], acc[mi][ni], 0, 0, 0);
    }
    __syncthreads();
  }
  int mbase = bm * 64 + wr * 32;
  int nbase = bn * 64 + wc * 32;
  #pragma unroll
  for (int mi = 0; mi < 2; ++mi)
    #pragma unroll
    for (int ni = 0; ni < 2; ++ni)
      #pragma unroll
      for (int r = 0; r < 4; ++r) {
        int gm = mbase + mi * 16 + hi * 4 + r;
        int gn = nbase + ni * 16 + lo;
        float v = acc[mi][ni][r] + (g.rowbias ? g.bias[gm] : g.bias[gn]);
        if (GELU) v = 0.5f * v * (1.0f + erff(v * 0.70710678118654752f));
        if (OUTBF) ((unsigned short*)g.C)[(size_t)gm * g.N + gn] = f2bf(v);
        else       ((float*)g.C)[(size_t)gm * g.N + gn] = v;
      }
}

// ---------------- fused attention per (b,h): Qproj + QK^T + softmax + PV ----------------
// LDS: Qd 8K | KP 64K (K tiles, later P) | Vd 64K | pm 4K | red 1K | red2 1K | rnv 256B
#define ATTN_LDS 145664
__global__ __launch_bounds__(256) void attn_kernel(
    const unsigned short* __restrict__ qbuf, const unsigned short* __restrict__ WqTl,
    const float* __restrict__ bql, const unsigned short* __restrict__ khb,
    const unsigned short* __restrict__ vTall, const unsigned long long* __restrict__ pmask,
    unsigned short* __restrict__ ctx) {
  extern __shared__ char lds[];
  char* Qd = lds;
  char* KP = lds + 8192;
  char* Vd = lds + 8192 + 65536;
  unsigned long long* pm = (unsigned long long*)(lds + 139264);
  float* red  = (float*)(lds + 143360);
  float* red2 = (float*)(lds + 144384);
  float* rnv  = (float*)(lds + 145408);
  int bh = blockIdx.x;
  int b = bh / HH, h = bh - b * HH;
  int t = threadIdx.x, w = t >> 6, l = t & 63, hi = l >> 4, lo = l & 15;
  int o16 = l * 16, ro = o16 >> 7, cb = o16 & 127;

  // issue V staging (vT rows h*64.., cols b*512..; row stride 4096 B)
  const char* vsrc = (const char*)vTall + (size_t)(h * 64) * 4096 + (size_t)b * 1024;
  #pragma unroll
  for (int rr = 0; rr < 16; ++rr) {
    int rv = w * 16 + rr;
    gload_lds16(vsrc + (size_t)rv * 4096 + ((l * 16) ^ ((rv & 7) << 4)), Vd + rv * 1024);
  }
  // pm staging (64 rows x 64B)
  if (w == 0) {
    const char* psrc = (const char*)pmask + (size_t)b * 4096;
    #pragma unroll
    for (int c = 0; c < 4; ++c) gload_lds16(psrc + c * 1024 + l * 16, (char*)pm + c * 1024);
  }

  // ---- Q projection (pipelined, staging in KP region: A0/B0/A1/B1 8K each) ----
  const char* Aq = (const char*)qbuf + (size_t)(b * II) * 1536;
  const char* Bq = (const char*)WqTl + (size_t)(h * 64) * 1536;
  f32x4 qacc[4] = {};
  #pragma unroll
  for (int cc = 0; cc < 2; ++cc) {
    int ch = w * 2 + cc, row = ch * 8 + ro;
    int scb = cb ^ ((row & 7) << 4);
    gload_lds16(Aq + (size_t)row * 1536 + scb, KP + ch * 1024);
    gload_lds16(Bq + (size_t)row * 1536 + scb, KP + 8192 + ch * 1024);
  }
  __syncthreads();
  for (int kt = 0; kt < 12; ++kt) {
    int cur = (kt & 1) * 16384;
    if (kt < 11) {
      int nxt = ((kt + 1) & 1) * 16384;
      int kb = (kt + 1) * 128;
      #pragma unroll
      for (int cc = 0; cc < 2; ++cc) {
        int ch = w * 2 + cc, row = ch * 8 + ro;
        int scb = kb + (cb ^ ((row & 7) << 4));
        gload_lds16(Aq + (size_t)row * 1536 + scb, KP + nxt + ch * 1024);
        gload_lds16(Bq + (size_t)row * 1536 + scb, KP + nxt + 8192 + ch * 1024);
      }
    }
    #pragma unroll
    for (int kk = 0; kk < 2; ++kk) {
      int ra = w * 16 + lo;
      short8 av = *(const short8*)(KP + cur + ra * 128 + ((kk * 64 + hi * 16) ^ ((ra & 7) << 4)));
      #pragma unroll
      for (int ni = 0; ni < 4; ++ni) {
        int rb = ni * 16 + lo;
        short8 bv = *(const short8*)(KP + cur + 8192 + rb * 128 + ((kk * 64 + hi * 16) ^ ((rb & 7) << 4)));
        qacc[ni] = __builtin_amdgcn_mfma_f32_16x16x32_bf16(av, bv, qacc[ni], 0, 0, 0);
      }
    }
    __syncthreads();
  }
  // write Q (bf16, swizzled [64][128B])
  #pragma unroll
  for (int ni = 0; ni < 4; ++ni)
    #pragma unroll
    for (int r = 0; r < 4; ++r) {
      int row = w * 16 + hi * 4 + r, col = ni * 16 + lo;
      float v = qacc[ni][r] + bql[h * 64 + col];
      *(unsigned short*)(Qd + row * 128 + ((col * 2) ^ ((row & 7) << 4))) = f2bf(v);
    }
  // ---- stage K (512 rows x 128B) ----
  const char* Ks = (const char*)khb + (size_t)(b * SS) * 1536 + h * 128;
  #pragma unroll
  for (int cc = 0; cc < 16; ++cc) {
    int ch = w * 16 + cc, row = ch * 8 + ro;
    int scb = cb ^ ((row & 7) << 4);
    gload_lds16(Ks + (size_t)row * 1536 + scb, KP + ch * 1024);
  }
  __syncthreads();

  // ---- QK^T: wave w owns cols w*128..w*128+127, all 64 rows ----
  f32x4 acc[4][8] = {};
  #pragma unroll
  for (int kk = 0; kk < 2; ++kk) {
    short8 av[4];
    #pragma unroll
    for (int mi = 0; mi < 4; ++mi) {
      int ra = mi * 16 + lo;
      av[mi] = *(const short8*)(Qd + ra * 128 + ((kk * 64 + hi * 16) ^ ((ra & 7) << 4)));
    }
    #pragma unroll
    for (int ni = 0; ni < 8; ++ni) {
      int rk = w * 128 + ni * 16 + lo;
      short8 bv = *(const short8*)(KP + rk * 128 + ((kk * 64 + hi * 16) ^ ((rk & 7) << 4)));
      #pragma unroll
      for (int mi = 0; mi < 4; ++mi)
        acc[mi][ni] = __builtin_amdgcn_mfma_f32_16x16x32_bf16(av[mi], bv, acc[mi][ni], 0, 0, 0);
    }
  }
  // ---- row max (raw scores; softmax is shift-invariant) ----
  #pragma unroll
  for (int mi = 0; mi < 4; ++mi)
    #pragma unroll
    for (int r = 0; r < 4; ++r) {
      float m = acc[mi][0][r];
      #pragma unroll
      for (int ni = 1; ni < 8; ++ni) m = fmaxf(m, acc[mi][ni][r]);
      #pragma unroll
      for (int xm = 1; xm <= 8; xm <<= 1) m = fmaxf(m, __shfl_xor(m, xm));
      if (lo == 0) red[(mi * 16 + hi * 4 + r) * 4 + w] = m;
    }
  __syncthreads();
  // ---- exp * inclusion + sum; write P (unnormalized bf16) over K region ----
  #pragma unroll
  for (int mi = 0; mi < 4; ++mi)
    #pragma unroll
    for (int r = 0; r < 4; ++r) {
      int row = mi * 16 + hi * 4 + r;
      float4 rm4 = *(const float4*)&red[row * 4];
      float gm = fmaxf(fmaxf(rm4.x, rm4.y), fmaxf(rm4.z, rm4.w));
      unsigned long long w0 = pm[row * 8 + w * 2 + 0];
      unsigned long long w1 = pm[row * 8 + w * 2 + 1];
      float s = 0.f;
      #pragma unroll
      for (int ni = 0; ni < 8; ++ni) {
        int sl = ni * 16 + lo;
        unsigned long long word = (sl < 64) ? w0 : w1;
        float in = ((word >> (sl & 63)) & 1ull) ? 1.0f : 0.0f;
        float e = __expf((acc[mi][ni][r] - gm) * 0.125f) * in;
        s += e;
        int sbyte = w * 256 + ni * 32 + lo * 2;
        *(unsigned short*)(KP + row * 1024 + (sbyte ^ ((row & 7) << 4))) = f2bf(e);
      }
      #pragma unroll
      for (int xm = 1; xm <= 8; xm <<= 1) s += __shfl_xor(s, xm);
      if (lo == 0) red2[row * 4 + w] = s;
    }
  __syncthreads();
  if (w == 0 && lo == 0) {
    #pragma unroll
    for (int mi = 0; mi < 4; ++mi)
      #pragma unroll
      for (int r = 0; r < 4; ++r) {
        int row = mi * 16 + hi * 4 + r;
        float4 s4 = *(const float4*)&red2[row * 4];
        rnv[row] = 1.0f / ((s4.x + s4.y) + (s4.z + s4.w));
      }
  }
  __syncthreads();
  // ---- PV: wave w owns output cols w*16..w*16+15, rows all 64, K=512 ----
  f32x4 pacc[4] = {};
  for (int kk = 0; kk < 16; ++kk) {
    int rv = w * 16 + lo;
    short8 bv = *(const short8*)(Vd + rv * 1024 + ((kk * 64 + hi * 16) ^ ((rv & 7) << 4)));
    #pragma unroll
    for (int mi = 0; mi < 4; ++mi) {
      int ra = mi * 16 + lo;
      short8 av = *(const short8*)(KP + ra * 1024 + ((kk * 64 + hi * 16) ^ ((ra & 7) << 4)));
      pacc[mi] = __builtin_amdgcn_mfma_f32_16x16x32_bf16(av, bv, pacc[mi], 0, 0, 0);
    }
  }
  #pragma unroll
  for (int mi = 0; mi < 4; ++mi)
    #pragma unroll
    for (int r = 0; r < 4; ++r) {
      int row = mi * 16 + hi * 4 + r;
      ctx[(size_t)(b * II + row) * DD + h * 64 + w * 16 + lo] = f2bf(pacc[mi][r] * rnv[row]);
    }
}

// ---------------- residual + LayerNorm ----------------
__global__ __launch_bounds__(256) void ln_kernel(const float* __restrict__ x, const float* __restrict__ y,
                                                 const float* __restrict__ g, const float* __restrict__ bb,
                                                 float* __restrict__ qf, unsigned short* __restrict__ qb) {
  __shared__ float r1[4], r2[4];
  int r = blockIdx.x, t = threadIdx.x;
  size_t o = (size_t)r * DD;
  float v0 = x[o + t] + y[o + t];
  float v1 = x[o + t + 256] + y[o + t + 256];
  float v2 = x[o + t + 512] + y[o + t + 512];
  float s = v0 + v1 + v2, ss = v0 * v0 + v1 * v1 + v2 * v2;
  #pragma unroll
  for (int o2 = 32; o2; o2 >>= 1) { s += __shfl_xor(s, o2); ss += __shfl_xor(ss, o2); }
  if ((t & 63) == 0) { r1[t >> 6] = s; r2[t >> 6] = ss; }
  __syncthreads();
  s = r1[0] + r1[1] + r1[2] + r1[3];
  ss = r2[0] + r2[1] + r2[2] + r2[3];
  float mean = s * (1.0f / DD);
  float var = ss * (1.0f / DD) - mean * mean;
  float inv = rsqrtf(var + 1e-12f);
  float w0 = (v0 - mean) * inv * g[t] + bb[t];
  float w1 = (v1 - mean) * inv * g[t + 256] + bb[t + 256];
  float w2 = (v2 - mean) * inv * g[t + 512] + bb[t + 512];
  qf[o + t] = w0; qf[o + t + 256] = w1; qf[o + t + 512] = w2;
  qb[o + t] = f2bf(w0); qb[o + t + 256] = f2bf(w1); qb[o + t + 512] = f2bf(w2);
}

// ---------------- final zero-context substitution ----------------
__global__ __launch_bounds__(256) void final_kernel(const float* __restrict__ q, const int* __restrict__ zi,
                                                    const float* __restrict__ zc, float* __restrict__ out) {
  int idx = blockIdx.x * 256 + threadIdx.x;
  int bi = idx / DD, d = idx - bi * DD;
  out[idx] = zi[bi] ? zc[d] : q[idx];
}

extern "C" void kernel_launch(void* const* d_in, const int* in_sizes, int n_in,
                              void* d_out, int out_size, void* d_ws, size_t ws_size,
                              hipStream_t stream) {
  (void)in_sizes; (void)n_in; (void)out_size; (void)ws_size;
  const float* hs0 = (const float*)d_in[0];
  const float* hs1 = (const float*)d_in[1];
  const float* Wq  = (const float*)d_in[3];
  const float* bq  = (const float*)d_in[4];
  const float* Wk  = (const float*)d_in[5];
  const float* bk  = (const float*)d_in[6];
  const float* Wv  = (const float*)d_in[7];
  const float* bv  = (const float*)d_in[8];
  const float* Wo  = (const float*)d_in[9];
  const float* bo  = (const float*)d_in[10];
  const float* ln1g = (const float*)d_in[11];
  const float* ln1b = (const float*)d_in[12];
  const float* W1  = (const float*)d_in[13];
  const float* b1  = (const float*)d_in[14];
  const float* W2  = (const float*)d_in[15];
  const float* b2  = (const float*)d_in[16];
  const float* ln2g = (const float*)d_in[17];
  const float* ln2b = (const float*)d_in[18];
  const float* zc  = (const float*)d_in[19];
  const int*   mask = (const int*)d_in[20];

  char* ws = (char*)d_ws;
  size_t off = 0;
  auto alloc = [&](size_t bytes) { size_t o = off; off += (bytes + 255) & ~(size_t)255; return o; };

  unsigned short* WT4 = (unsigned short*)(ws + alloc((size_t)4 * LL * DD * DD * 2));
  unsigned short* W1T = (unsigned short*)(ws + alloc((size_t)LL * FF * DD * 2));
  unsigned short* W2T = (unsigned short*)(ws + alloc((size_t)LL * DD * FF * 2));
  unsigned short* hsb = (unsigned short*)(ws + alloc((size_t)2 * BB * SS * DD * 2));
  float*          qf  = (float*)(ws + alloc((size_t)BB * II * DD * 4));
  unsigned short* qb  = (unsigned short*)(ws + alloc((size_t)BB * II * DD * 2));
  unsigned short* khb = (unsigned short*)(ws + alloc((size_t)BB * SS * DD * 2));
  unsigned short* vTall = (unsigned short*)(ws + alloc((size_t)DD * BB * SS * 2));  // [768][2048]
  unsigned short* ctxb = (unsigned short*)(ws + alloc((size_t)BB * II * DD * 2));
  float*          att_o = (float*)(ws + alloc((size_t)BB * II * DD * 4));
  unsigned short* ffh = (unsigned short*)(ws + alloc((size_t)BB * II * FF * 2));
  float*          ffo = (float*)(ws + alloc((size_t)BB * II * DD * 4));
  unsigned long long* pmask = (unsigned long long*)(ws + alloc((size_t)BB * II * 8 * 8));
  int*            zib = (int*)(ws + alloc((size_t)BB * II * 4));

  unsigned short* WqT = WT4 + 0 * (size_t)LL * DD * DD;
  unsigned short* WkT = WT4 + 1 * (size_t)LL * DD * DD;
  unsigned short* WvT = WT4 + 2 * (size_t)LL * DD * DD;
  unsigned short* WoT = WT4 + 3 * (size_t)LL * DD * DD;

  (void)hipFuncSetAttribute((const void*)attn_kernel,
                            hipFuncAttributeMaxDynamicSharedMemorySize, ATTN_LDS);

  dim3 tb(32, 8);
  T4 t4 = { { Wq, Wk, Wv, Wo } };
  tcast4_kernel<<<dim3(DD / 32, DD / 32, 4 * LL), tb, 0, stream>>>(t4, WT4);
  tcast_kernel<<<dim3(FF / 32, DD / 32, LL), tb, 0, stream>>>(W1, W1T, DD, FF);
  tcast_kernel<<<dim3(DD / 32, FF / 32, LL), tb, 0, stream>>>(W2, W2T, FF, DD);
  cast2_kernel<<<(BB * SS * DD / 4) / 256, 256, 0, stream>>>(hs0, hs1, hsb, hsb + (size_t)BB * SS * DD);
  pool_kernel<<<dim3(BB * II, 3), 256, 0, stream>>>(hs0, mask, zib, qf, qb, pmask);

  for (int l = 0; l < LL; ++l) {
    const unsigned short* hsl = hsb + (size_t)l * BB * SS * DD;
    // z=0: K projection [2048][768]; z=1: V^T = WvT @ hs^T -> [768][2048] (row bias)
    GB gK = { hsl, WkT + (size_t)l * DD * DD, bk + l * DD, khb, BB * SS, DD, 0 };
    GB gV = { WvT + (size_t)l * DD * DD, hsl, bv + l * DD, vTall, DD, BB * SS, 1 };
    gemm_nt<0, 1><<<dim3(16, 6, 2), 256, 0, stream>>>(gK, gV, DD);
    // fused attention (includes Q projection)
    attn_kernel<<<dim3(BB * HH), 256, ATTN_LDS, stream>>>(
        qb, WqT + (size_t)l * DD * DD, bq + l * DD, khb, vTall, pmask, ctxb);
    // Wo projection
    GB gO = { ctxb, WoT + (size_t)l * DD * DD, bo + l * DD, att_o, BB * II, DD, 0 };
    gemm_nt64<0, 0><<<dim3(4, 12), 256, 0, stream>>>(gO, DD);
    // LN1
    ln_kernel<<<BB * II, 256, 0, stream>>>(qf, att_o, ln1g + l * DD, ln1b + l * DD, qf, qb);
    // FFN1 (GELU)
    GB gF1 = { qb, W1T + (size_t)l * FF * DD, b1 + l * FF, ffh, BB * II, FF, 0 };
    gemm_nt64<1, 1><<<dim3(4, FF / 64), 256, 0, stream>>>(gF1, DD);
    // FFN2
    GB gF2 = { ffh, W2T + (size_t)l * DD * FF, b2 + l * DD, ffo, BB * II, DD, 0 };
    gemm_nt64<0, 0><<<dim3(4, 12), 256, 0, stream>>>(gF2, FF);
    // LN2
    ln_kernel<<<BB * II, 256, 0, stream>>>(qf, ffo, ln2g + l * DD, ln2b + l * DD, qf, qb);
  }
  final_kernel<<<(BB * II * DD) / 256, 256, 0, stream>>>(qf, zib, zc, (float*)d_out);
}